// Round 1
// baseline (1728.402 us; speedup 1.0000x reference)
//
#include <hip/hip_runtime.h>
#include <math.h>

// ---------------------------------------------------------------------------
// GAT forward (3 layers) on MI355X. f32 throughout (correctness-first round).
// N=50000 nodes, D=128, H=2 heads, k=64. E=800000 edges + N self-loops.
// ---------------------------------------------------------------------------

__device__ __forceinline__ unsigned int fkey(float f) {
    unsigned int u = __float_as_uint(f);
    return (u & 0x80000000u) ? ~u : (u | 0x80000000u);
}
__device__ __forceinline__ float funkey(unsigned int k) {
    unsigned int u = (k & 0x80000000u) ? (k ^ 0x80000000u) : ~k;
    return __uint_as_float(u);
}

// C = A(N x 128) @ W^T(128 x 128).  64-row tiles, W transposed into LDS.
__global__ __launch_bounds__(256) void gemm128(const float* __restrict__ A,
                                               const float* __restrict__ Wm,
                                               float* __restrict__ C, int N) {
    __shared__ float As[64][68];    // 64 rows x 64 k (one K-half), padded
    __shared__ float Wt[64][132];   // 64 k x 128 cols, padded (16B-aligned stride)
    const int tx = threadIdx.x;
    const int row0 = blockIdx.x * 64;
    const int cid = tx & 31;   // cols cid*4 .. cid*4+3
    const int rid = tx >> 5;   // rows rid*8 .. rid*8+7
    float acc[8][4] = {};
    const float4* A4 = (const float4*)A;
    const float4* W4 = (const float4*)Wm;

    for (int kt = 0; kt < 2; ++kt) {
        // load A K-half: 64 rows x 16 float4
        for (int i = tx; i < 1024; i += 256) {
            int r = i >> 4, q = i & 15;
            int row = row0 + r;
            float4 v = (row < N) ? A4[(size_t)row * 32 + kt * 16 + q]
                                 : make_float4(0.f, 0.f, 0.f, 0.f);
            As[r][q * 4 + 0] = v.x; As[r][q * 4 + 1] = v.y;
            As[r][q * 4 + 2] = v.z; As[r][q * 4 + 3] = v.w;
        }
        // load W K-half transposed: 128 rows(c) x 16 float4(k)
        for (int i = tx; i < 2048; i += 256) {
            int c = i >> 4, q = i & 15;
            float4 v = W4[(size_t)c * 32 + kt * 16 + q];
            Wt[q * 4 + 0][c] = v.x; Wt[q * 4 + 1][c] = v.y;
            Wt[q * 4 + 2][c] = v.z; Wt[q * 4 + 3][c] = v.w;
        }
        __syncthreads();
        #pragma unroll 8
        for (int k = 0; k < 64; ++k) {
            float4 w = *(const float4*)&Wt[k][cid * 4];
            float a[8];
            #pragma unroll
            for (int i = 0; i < 8; ++i) a[i] = As[rid * 8 + i][k];
            #pragma unroll
            for (int i = 0; i < 8; ++i) {
                acc[i][0] += a[i] * w.x; acc[i][1] += a[i] * w.y;
                acc[i][2] += a[i] * w.z; acc[i][3] += a[i] * w.w;
            }
        }
        __syncthreads();
    }
    #pragma unroll
    for (int i = 0; i < 8; ++i) {
        int row = row0 + rid * 8 + i;
        if (row < N)
            ((float4*)C)[(size_t)row * 32 + cid] =
                make_float4(acc[i][0], acc[i][1], acc[i][2], acc[i][3]);
    }
}

// Per-node attention coefficients: one wave per node.
// a_dst[n,h] = dot(x[n,h,:], att[h][0:64]); a_src[n,h] = dot(x[n,h,:], att[h][64:128])
__global__ __launch_bounds__(256) void att_node(const float* __restrict__ xlin,
                                                const float* __restrict__ att,
                                                float* __restrict__ a_src,
                                                float* __restrict__ a_dst, int N) {
    int n = blockIdx.x * 4 + (threadIdx.x >> 6);
    int l = threadIdx.x & 63;
    if (n >= N) return;
    float x0 = xlin[(size_t)n * 128 + l];
    float x1 = xlin[(size_t)n * 128 + 64 + l];
    float pd0 = x0 * att[l];        float ps0 = x0 * att[64 + l];
    float pd1 = x1 * att[128 + l];  float ps1 = x1 * att[192 + l];
    #pragma unroll
    for (int m = 32; m; m >>= 1) {
        pd0 += __shfl_xor(pd0, m);
        ps0 += __shfl_xor(ps0, m);
        pd1 += __shfl_xor(pd1, m);
        ps1 += __shfl_xor(ps1, m);
    }
    if (l == 0) {
        a_dst[n * 2 + 0] = pd0; a_dst[n * 2 + 1] = pd1;
        a_src[n * 2 + 0] = ps0; a_src[n * 2 + 1] = ps1;
    }
}

// Per-edge raw alpha + segment-max by src (uint-keyed float atomicMax).
__global__ __launch_bounds__(256) void edge_alpha(const int* __restrict__ ei, int E, int Et,
                                                  const float* __restrict__ a_src,
                                                  const float* __restrict__ a_dst,
                                                  float* __restrict__ alphaE,
                                                  unsigned int* __restrict__ mkey) {
    int e = blockIdx.x * 256 + threadIdx.x;
    if (e >= Et) return;
    int s, d;
    if (e < E) { s = ei[e]; d = ei[E + e]; } else { s = d = e - E; }
    #pragma unroll
    for (int h = 0; h < 2; ++h) {
        float al = a_dst[d * 2 + h] + a_src[s * 2 + h];
        al = (al > 0.f) ? al : 0.2f * al;   // leaky_relu slope 0.2
        alphaE[(size_t)e * 2 + h] = al;
        atomicMax(&mkey[s * 2 + h], fkey(al));
    }
}

// exp(alpha - max) + segment-sum by src.
__global__ __launch_bounds__(256) void edge_exp(const int* __restrict__ ei, int E, int Et,
                                                float* __restrict__ alphaE,
                                                const unsigned int* __restrict__ mkey,
                                                float* __restrict__ ssum) {
    int e = blockIdx.x * 256 + threadIdx.x;
    if (e >= Et) return;
    int s = (e < E) ? ei[e] : (e - E);
    #pragma unroll
    for (int h = 0; h < 2; ++h) {
        float m = funkey(mkey[s * 2 + h]);
        float ev = __expf(alphaE[(size_t)e * 2 + h] - m);
        alphaE[(size_t)e * 2 + h] = ev;
        atomicAdd(&ssum[s * 2 + h], ev);
    }
}

// Aggregate messages to dst: one wave per edge, lane handles feat l and l+64.
__global__ __launch_bounds__(256) void edge_agg(const int* __restrict__ ei, int E, int Et,
                                                const float* __restrict__ xlin,
                                                const float* __restrict__ alphaE,
                                                const float* __restrict__ ssum,
                                                float* __restrict__ agg) {
    int w = blockIdx.x * 4 + (threadIdx.x >> 6);
    int l = threadIdx.x & 63;
    if (w >= Et) return;
    int s, d;
    if (w < E) { s = ei[w]; d = ei[E + w]; } else { s = d = w - E; }
    float w0 = alphaE[(size_t)w * 2 + 0] / (ssum[s * 2 + 0] + 1e-16f);
    float w1 = alphaE[(size_t)w * 2 + 1] / (ssum[s * 2 + 1] + 1e-16f);
    float v0 = xlin[(size_t)s * 128 + l] * w0;
    float v1 = xlin[(size_t)s * 128 + 64 + l] * w1;
    atomicAdd(&agg[(size_t)d * 128 + l], v0);
    atomicAdd(&agg[(size_t)d * 128 + 64 + l], v1);
}

// out = relu(agg + bias); optionally mirror to x_embed output.
__global__ __launch_bounds__(256) void bias_relu(float* __restrict__ hb,
                                                 const float* __restrict__ bias,
                                                 float* __restrict__ xout, int total) {
    int i = blockIdx.x * 256 + threadIdx.x;
    if (i >= total) return;
    float v = hb[i] + bias[i & 127];
    v = (v > 0.f) ? v : 0.f;
    hb[i] = v;
    if (xout) xout[i] = v;
}

// Final projection (N x 3) + argmax. One wave per node.
__global__ __launch_bounds__(256) void out_proj(const float* __restrict__ h,
                                                const float* __restrict__ Wout,
                                                const float* __restrict__ bout,
                                                float* __restrict__ out3,
                                                float* __restrict__ ypred, int N) {
    int n = blockIdx.x * 4 + (threadIdx.x >> 6);
    int l = threadIdx.x & 63;
    if (n >= N) return;
    float x0 = h[(size_t)n * 128 + l];
    float x1 = h[(size_t)n * 128 + 64 + l];
    float p0 = x0 * Wout[l]       + x1 * Wout[64 + l];
    float p1 = x0 * Wout[128 + l] + x1 * Wout[192 + l];
    float p2 = x0 * Wout[256 + l] + x1 * Wout[320 + l];
    #pragma unroll
    for (int m = 32; m; m >>= 1) {
        p0 += __shfl_xor(p0, m);
        p1 += __shfl_xor(p1, m);
        p2 += __shfl_xor(p2, m);
    }
    if (l == 0) {
        p0 += bout[0]; p1 += bout[1]; p2 += bout[2];
        out3[n * 3 + 0] = p0; out3[n * 3 + 1] = p1; out3[n * 3 + 2] = p2;
        int am = 0; float best = p0;
        if (p1 > best) { best = p1; am = 1; }
        if (p2 > best) { best = p2; am = 2; }
        ypred[n] = (float)am;
    }
}

__global__ __launch_bounds__(256) void gather_out(const float* __restrict__ out3,
                                                  const float* __restrict__ ypred,
                                                  const int* __restrict__ node_index,
                                                  float* __restrict__ node_out,
                                                  float* __restrict__ y_nodepred, int M) {
    int i = blockIdx.x * 256 + threadIdx.x;
    if (i >= M) return;
    int idx = node_index[i];
    node_out[i * 3 + 0] = out3[idx * 3 + 0];
    node_out[i * 3 + 1] = out3[idx * 3 + 1];
    node_out[i * 3 + 2] = out3[idx * 3 + 2];
    y_nodepred[i] = ypred[idx];
}

extern "C" void kernel_launch(void* const* d_in, const int* in_sizes, int n_in,
                              void* d_out, int out_size, void* d_ws, size_t ws_size,
                              hipStream_t stream) {
    const float* x          = (const float*)d_in[0];
    const int*   ei         = (const int*)d_in[1];
    const int*   node_index = (const int*)d_in[3];
    const float* W[3]   = {(const float*)d_in[4], (const float*)d_in[7], (const float*)d_in[10]};
    const float* att[3] = {(const float*)d_in[5], (const float*)d_in[8], (const float*)d_in[11]};
    const float* b[3]   = {(const float*)d_in[6], (const float*)d_in[9], (const float*)d_in[12]};
    const float* Wout = (const float*)d_in[13];
    const float* bout = (const float*)d_in[14];

    const int N  = in_sizes[0] / 128;
    const int E  = in_sizes[1] / 2;
    const int Et = E + N;
    const int M  = in_sizes[3];

    // workspace layout (floats)
    float* ws     = (float*)d_ws;
    float* xlin   = ws;                              // N*128
    float* hb     = xlin + (size_t)N * 128;          // N*128 (agg accumulator + layer output)
    float* a_src  = hb + (size_t)N * 128;            // N*2
    float* a_dst  = a_src + (size_t)N * 2;           // N*2
    float* ssum   = a_dst + (size_t)N * 2;           // N*2
    unsigned int* mkey = (unsigned int*)(ssum + (size_t)N * 2);  // N*2
    float* alphaE = (float*)(mkey + (size_t)N * 2);  // Et*2
    float* out3   = alphaE + (size_t)Et * 2;         // N*3

    // output layout (floats): x_embed | node_output | ypred | y_nodepred
    float* o_embed = (float*)d_out;
    float* o_node  = o_embed + (size_t)N * 128;
    float* o_ypred = o_node + (size_t)M * 3;
    float* o_ynode = o_ypred + (size_t)N;

    const int gemm_blocks = (N + 63) / 64;
    const int node_wave_blocks = (N + 3) / 4;
    const int edge_blocks = (Et + 255) / 256;
    const int edge_wave_blocks = (Et + 3) / 4;
    const int elem_blocks = ((size_t)N * 128 + 255) / 256;

    for (int L = 0; L < 3; ++L) {
        const float* hin = (L == 0) ? x : hb;
        gemm128<<<gemm_blocks, 256, 0, stream>>>(hin, W[L], xlin, N);
        att_node<<<node_wave_blocks, 256, 0, stream>>>(xlin, att[L], a_src, a_dst, N);
        hipMemsetAsync(hb, 0, (size_t)N * 128 * sizeof(float), stream);
        hipMemsetAsync(mkey, 0, (size_t)N * 2 * sizeof(unsigned int), stream);
        hipMemsetAsync(ssum, 0, (size_t)N * 2 * sizeof(float), stream);
        edge_alpha<<<edge_blocks, 256, 0, stream>>>(ei, E, Et, a_src, a_dst, alphaE, mkey);
        edge_exp<<<edge_blocks, 256, 0, stream>>>(ei, E, Et, alphaE, mkey, ssum);
        edge_agg<<<edge_wave_blocks, 256, 0, stream>>>(ei, E, Et, xlin, alphaE, ssum, hb);
        bias_relu<<<elem_blocks, 256, 0, stream>>>(hb, b[L], (L == 2) ? o_embed : nullptr,
                                                   N * 128);
    }
    out_proj<<<node_wave_blocks, 256, 0, stream>>>(hb, Wout, bout, out3, o_ypred, N);
    gather_out<<<(M + 255) / 256, 256, 0, stream>>>(out3, o_ypred, node_index, o_node, o_ynode, M);
}

// Round 2
// 1058.937 us; speedup vs baseline: 1.6322x; 1.6322x over previous
//
#include <hip/hip_runtime.h>
#include <math.h>

// ---------------------------------------------------------------------------
// GAT forward (3 layers) on MI355X. f32. N=50000, D=128, H=2, k=64.
// E=800000 real edges + N self-loops (Et = 850000).
// Round 2: CSR-by-dst aggregation (no per-edge atomic writes to N*128),
// softmax max-pass dropped (bounded exponent), bias/relu fused into agg.
// ---------------------------------------------------------------------------

// C = A(N x 128) @ W^T(128 x 128).  64-row tiles, W transposed into LDS.
__global__ __launch_bounds__(256) void gemm128(const float* __restrict__ A,
                                               const float* __restrict__ Wm,
                                               float* __restrict__ C, int N) {
    __shared__ float As[64][68];
    __shared__ float Wt[64][132];
    const int tx = threadIdx.x;
    const int row0 = blockIdx.x * 64;
    const int cid = tx & 31;
    const int rid = tx >> 5;
    float acc[8][4] = {};
    const float4* A4 = (const float4*)A;
    const float4* W4 = (const float4*)Wm;

    for (int kt = 0; kt < 2; ++kt) {
        for (int i = tx; i < 1024; i += 256) {
            int r = i >> 4, q = i & 15;
            int row = row0 + r;
            float4 v = (row < N) ? A4[(size_t)row * 32 + kt * 16 + q]
                                 : make_float4(0.f, 0.f, 0.f, 0.f);
            As[r][q * 4 + 0] = v.x; As[r][q * 4 + 1] = v.y;
            As[r][q * 4 + 2] = v.z; As[r][q * 4 + 3] = v.w;
        }
        for (int i = tx; i < 2048; i += 256) {
            int c = i >> 4, q = i & 15;
            float4 v = W4[(size_t)c * 32 + kt * 16 + q];
            Wt[q * 4 + 0][c] = v.x; Wt[q * 4 + 1][c] = v.y;
            Wt[q * 4 + 2][c] = v.z; Wt[q * 4 + 3][c] = v.w;
        }
        __syncthreads();
        #pragma unroll 8
        for (int k = 0; k < 64; ++k) {
            float4 w = *(const float4*)&Wt[k][cid * 4];
            float a[8];
            #pragma unroll
            for (int i = 0; i < 8; ++i) a[i] = As[rid * 8 + i][k];
            #pragma unroll
            for (int i = 0; i < 8; ++i) {
                acc[i][0] += a[i] * w.x; acc[i][1] += a[i] * w.y;
                acc[i][2] += a[i] * w.z; acc[i][3] += a[i] * w.w;
            }
        }
        __syncthreads();
    }
    #pragma unroll
    for (int i = 0; i < 8; ++i) {
        int row = row0 + rid * 8 + i;
        if (row < N)
            ((float4*)C)[(size_t)row * 32 + cid] =
                make_float4(acc[i][0], acc[i][1], acc[i][2], acc[i][3]);
    }
}

// Per-node attention coefficients: one wave per node.
__global__ __launch_bounds__(256) void att_node(const float* __restrict__ xlin,
                                                const float* __restrict__ att,
                                                float* __restrict__ a_src,
                                                float* __restrict__ a_dst, int N) {
    int n = blockIdx.x * 4 + (threadIdx.x >> 6);
    int l = threadIdx.x & 63;
    if (n >= N) return;
    float x0 = xlin[(size_t)n * 128 + l];
    float x1 = xlin[(size_t)n * 128 + 64 + l];
    float pd0 = x0 * att[l];        float ps0 = x0 * att[64 + l];
    float pd1 = x1 * att[128 + l];  float ps1 = x1 * att[192 + l];
    #pragma unroll
    for (int m = 32; m; m >>= 1) {
        pd0 += __shfl_xor(pd0, m);
        ps0 += __shfl_xor(ps0, m);
        pd1 += __shfl_xor(pd1, m);
        ps1 += __shfl_xor(ps1, m);
    }
    if (l == 0) {
        a_dst[n * 2 + 0] = pd0; a_dst[n * 2 + 1] = pd1;
        a_src[n * 2 + 0] = ps0; a_src[n * 2 + 1] = ps1;
    }
}

// ------------------------- CSR-by-dst build (once) -------------------------
__global__ __launch_bounds__(256) void init_deg(unsigned int* __restrict__ deg, int N) {
    int n = blockIdx.x * 256 + threadIdx.x;
    if (n < N) deg[n] = 1u;  // self-loop
}

__global__ __launch_bounds__(256) void hist_dst(const int* __restrict__ ei, int E,
                                                unsigned int* __restrict__ deg) {
    int e = blockIdx.x * 256 + threadIdx.x;
    if (e < E) atomicAdd(&deg[ei[E + e]], 1u);
}

// Single-block exclusive scan; deg becomes the cursor (start offsets).
__global__ __launch_bounds__(1024) void scan_off(unsigned int* __restrict__ deg,
                                                 unsigned int* __restrict__ off, int N) {
    __shared__ unsigned int part[1024];
    int t = threadIdx.x;
    int chunk = (N + 1023) / 1024;
    int lo = t * chunk, hi = lo + chunk; if (hi > N) hi = N; if (lo > N) lo = N;
    unsigned int s = 0;
    for (int i = lo; i < hi; ++i) s += deg[i];
    part[t] = s;
    __syncthreads();
    for (int d = 1; d < 1024; d <<= 1) {
        unsigned int v = (t >= d) ? part[t - d] : 0u;
        __syncthreads();
        part[t] += v;
        __syncthreads();
    }
    unsigned int run = (t == 0) ? 0u : part[t - 1];
    for (int i = lo; i < hi; ++i) {
        unsigned int dv = deg[i];
        off[i] = run;
        deg[i] = run;   // cursor
        run += dv;
    }
    if (t == 1023) off[N] = part[1023];
}

__global__ __launch_bounds__(256) void scatter_dst(const int* __restrict__ ei, int E, int Et,
                                                   unsigned int* __restrict__ cur,
                                                   unsigned int* __restrict__ eidx) {
    int e = blockIdx.x * 256 + threadIdx.x;
    if (e >= Et) return;
    int d = (e < E) ? ei[E + e] : (e - E);
    unsigned int pos = atomicAdd(&cur[d], 1u);
    eidx[pos] = (unsigned int)e;
}

// --------------- fused alpha + exp + segment-sum (by src) ------------------
__global__ __launch_bounds__(256) void edge_ae(const int* __restrict__ ei, int E, int Et,
                                               const float* __restrict__ a_src,
                                               const float* __restrict__ a_dst,
                                               float* __restrict__ alphaE,
                                               float* __restrict__ ssum) {
    int e = blockIdx.x * 256 + threadIdx.x;
    if (e >= Et) return;
    int s, d;
    if (e < E) { s = ei[e]; d = ei[E + e]; } else { s = d = e - E; }
    float2 ad = ((const float2*)a_dst)[d];
    float2 as = ((const float2*)a_src)[s];
    float al0 = ad.x + as.x; al0 = (al0 > 0.f) ? al0 : 0.2f * al0;
    float al1 = ad.y + as.y; al1 = (al1 > 0.f) ? al1 : 0.2f * al1;
    float e0 = __expf(al0), e1 = __expf(al1);
    ((float2*)alphaE)[e] = make_float2(e0, e1);
    atomicAdd(&ssum[s * 2 + 0], e0);
    atomicAdd(&ssum[s * 2 + 1], e1);
}

// ---------------- CSR aggregation: one wave per dst node -------------------
// lane l covers features 2l, 2l+1 (head = l<32 ? 0 : 1). Fuses /ssum, +bias,
// relu, and optional mirror to x_embed.
__global__ __launch_bounds__(256) void agg_csr(const int* __restrict__ ei, int E,
                                               const unsigned int* __restrict__ off,
                                               const unsigned int* __restrict__ eidx,
                                               const float* __restrict__ xlin,
                                               const float* __restrict__ alphaE,
                                               const float* __restrict__ ssum,
                                               const float* __restrict__ bias,
                                               float* __restrict__ out,
                                               float* __restrict__ mirror, int N) {
    int d = blockIdx.x * 4 + (threadIdx.x >> 6);
    int l = threadIdx.x & 63;
    if (d >= N) return;
    unsigned int j0 = off[d], j1 = off[d + 1];
    const float2* x2 = (const float2*)xlin;
    const float2* a2 = (const float2*)alphaE;
    const float2* s2 = (const float2*)ssum;
    float accx = 0.f, accy = 0.f;
    for (unsigned int j = j0; j < j1; ++j) {
        int e = (int)eidx[j];
        int s = (e < E) ? ei[e] : (e - E);
        float2 al = a2[e];
        float2 sm = s2[s];
        float w = (l < 32) ? (al.x / (sm.x + 1e-16f)) : (al.y / (sm.y + 1e-16f));
        float2 v = x2[(size_t)s * 64 + l];
        accx += v.x * w; accy += v.y * w;
    }
    float2 bb = ((const float2*)bias)[l];
    float o0 = fmaxf(accx + bb.x, 0.f);
    float o1 = fmaxf(accy + bb.y, 0.f);
    ((float2*)out)[(size_t)d * 64 + l] = make_float2(o0, o1);
    if (mirror) ((float2*)mirror)[(size_t)d * 64 + l] = make_float2(o0, o1);
}

// Final projection (N x 3) + argmax. One wave per node.
__global__ __launch_bounds__(256) void out_proj(const float* __restrict__ h,
                                                const float* __restrict__ Wout,
                                                const float* __restrict__ bout,
                                                float* __restrict__ out3,
                                                float* __restrict__ ypred, int N) {
    int n = blockIdx.x * 4 + (threadIdx.x >> 6);
    int l = threadIdx.x & 63;
    if (n >= N) return;
    float x0 = h[(size_t)n * 128 + l];
    float x1 = h[(size_t)n * 128 + 64 + l];
    float p0 = x0 * Wout[l]       + x1 * Wout[64 + l];
    float p1 = x0 * Wout[128 + l] + x1 * Wout[192 + l];
    float p2 = x0 * Wout[256 + l] + x1 * Wout[320 + l];
    #pragma unroll
    for (int m = 32; m; m >>= 1) {
        p0 += __shfl_xor(p0, m);
        p1 += __shfl_xor(p1, m);
        p2 += __shfl_xor(p2, m);
    }
    if (l == 0) {
        p0 += bout[0]; p1 += bout[1]; p2 += bout[2];
        out3[n * 3 + 0] = p0; out3[n * 3 + 1] = p1; out3[n * 3 + 2] = p2;
        int am = 0; float best = p0;
        if (p1 > best) { best = p1; am = 1; }
        if (p2 > best) { best = p2; am = 2; }
        ypred[n] = (float)am;
    }
}

__global__ __launch_bounds__(256) void gather_out(const float* __restrict__ out3,
                                                  const float* __restrict__ ypred,
                                                  const int* __restrict__ node_index,
                                                  float* __restrict__ node_out,
                                                  float* __restrict__ y_nodepred, int M) {
    int i = blockIdx.x * 256 + threadIdx.x;
    if (i >= M) return;
    int idx = node_index[i];
    node_out[i * 3 + 0] = out3[idx * 3 + 0];
    node_out[i * 3 + 1] = out3[idx * 3 + 1];
    node_out[i * 3 + 2] = out3[idx * 3 + 2];
    y_nodepred[i] = ypred[idx];
}

extern "C" void kernel_launch(void* const* d_in, const int* in_sizes, int n_in,
                              void* d_out, int out_size, void* d_ws, size_t ws_size,
                              hipStream_t stream) {
    const float* x          = (const float*)d_in[0];
    const int*   ei         = (const int*)d_in[1];
    const int*   node_index = (const int*)d_in[3];
    const float* W[3]   = {(const float*)d_in[4], (const float*)d_in[7], (const float*)d_in[10]};
    const float* att[3] = {(const float*)d_in[5], (const float*)d_in[8], (const float*)d_in[11]};
    const float* b[3]   = {(const float*)d_in[6], (const float*)d_in[9], (const float*)d_in[12]};
    const float* Wout = (const float*)d_in[13];
    const float* bout = (const float*)d_in[14];

    const int N  = in_sizes[0] / 128;
    const int E  = in_sizes[1] / 2;
    const int Et = E + N;
    const int M  = in_sizes[3];

    // workspace layout (floats), ~63 MB total
    float* ws     = (float*)d_ws;
    float* xlin   = ws;                               // N*128
    float* hb     = xlin + (size_t)N * 128;           // N*128
    float* a_src  = hb + (size_t)N * 128;             // N*2
    float* a_dst  = a_src + (size_t)N * 2;            // N*2
    float* ssum   = a_dst + (size_t)N * 2;            // N*2
    float* alphaE = ssum + (size_t)N * 2;             // Et*2   (out3 aliases here at the end)
    unsigned int* off  = (unsigned int*)(alphaE + (size_t)Et * 2);  // N+1 (padded to N+4)
    unsigned int* deg  = off + (size_t)N + 4;                        // N (also scatter cursor)
    unsigned int* eidx = deg + (size_t)N;                            // Et
    float* out3 = alphaE;                             // reuse after last agg

    // output layout (floats): x_embed | node_output | ypred | y_nodepred
    float* o_embed = (float*)d_out;
    float* o_node  = o_embed + (size_t)N * 128;
    float* o_ypred = o_node + (size_t)M * 3;
    float* o_ynode = o_ypred + (size_t)N;

    const int gemm_blocks = (N + 63) / 64;
    const int node_wave_blocks = (N + 3) / 4;
    const int edge_blocks = (Et + 255) / 256;
    const int n_blocks = (N + 255) / 256;

    // ---- CSR by dst (built once, reused for all 3 layers) ----
    init_deg<<<n_blocks, 256, 0, stream>>>(deg, N);
    hist_dst<<<(E + 255) / 256, 256, 0, stream>>>(ei, E, deg);
    scan_off<<<1, 1024, 0, stream>>>(deg, off, N);
    scatter_dst<<<edge_blocks, 256, 0, stream>>>(ei, E, Et, deg, eidx);

    for (int L = 0; L < 3; ++L) {
        const float* hin = (L == 0) ? x : hb;
        gemm128<<<gemm_blocks, 256, 0, stream>>>(hin, W[L], xlin, N);
        att_node<<<node_wave_blocks, 256, 0, stream>>>(xlin, att[L], a_src, a_dst, N);
        hipMemsetAsync(ssum, 0, (size_t)N * 2 * sizeof(float), stream);
        edge_ae<<<edge_blocks, 256, 0, stream>>>(ei, E, Et, a_src, a_dst, alphaE, ssum);
        agg_csr<<<node_wave_blocks, 256, 0, stream>>>(ei, E, off, eidx, xlin, alphaE, ssum,
                                                      b[L], hb, (L == 2) ? o_embed : nullptr, N);
    }
    out_proj<<<node_wave_blocks, 256, 0, stream>>>(hb, Wout, bout, out3, o_ypred, N);
    gather_out<<<(M + 255) / 256, 256, 0, stream>>>(out3, o_ypred, node_index, o_node, o_ynode, M);
}

// Round 3
// 893.807 us; speedup vs baseline: 1.9338x; 1.1847x over previous
//
#include <hip/hip_runtime.h>
#include <math.h>

// ---------------------------------------------------------------------------
// GAT forward (3 layers) on MI355X. f32. N=50000, D=128, H=2, k=64.
// E=800000 real edges + N self-loops (Et=850000).
// Round 3: CSR-ordered alpha scatter + src list + reciprocal table =>
// agg loop has a single dependent gather level; unroll-4 for MLP;
// out_proj fused into last agg; ssum-zero fused into att_node.
// ---------------------------------------------------------------------------

// C = A(N x 128) @ W^T(128 x 128).  64-row tiles, W transposed into LDS.
__global__ __launch_bounds__(256) void gemm128(const float* __restrict__ A,
                                               const float* __restrict__ Wm,
                                               float* __restrict__ C, int N) {
    __shared__ float As[64][68];
    __shared__ float Wt[64][132];
    const int tx = threadIdx.x;
    const int row0 = blockIdx.x * 64;
    const int cid = tx & 31;
    const int rid = tx >> 5;
    float acc[8][4] = {};
    const float4* A4 = (const float4*)A;
    const float4* W4 = (const float4*)Wm;

    for (int kt = 0; kt < 2; ++kt) {
        for (int i = tx; i < 1024; i += 256) {
            int r = i >> 4, q = i & 15;
            int row = row0 + r;
            float4 v = (row < N) ? A4[(size_t)row * 32 + kt * 16 + q]
                                 : make_float4(0.f, 0.f, 0.f, 0.f);
            As[r][q * 4 + 0] = v.x; As[r][q * 4 + 1] = v.y;
            As[r][q * 4 + 2] = v.z; As[r][q * 4 + 3] = v.w;
        }
        for (int i = tx; i < 2048; i += 256) {
            int c = i >> 4, q = i & 15;
            float4 v = W4[(size_t)c * 32 + kt * 16 + q];
            Wt[q * 4 + 0][c] = v.x; Wt[q * 4 + 1][c] = v.y;
            Wt[q * 4 + 2][c] = v.z; Wt[q * 4 + 3][c] = v.w;
        }
        __syncthreads();
        #pragma unroll 8
        for (int k = 0; k < 64; ++k) {
            float4 w = *(const float4*)&Wt[k][cid * 4];
            float a[8];
            #pragma unroll
            for (int i = 0; i < 8; ++i) a[i] = As[rid * 8 + i][k];
            #pragma unroll
            for (int i = 0; i < 8; ++i) {
                acc[i][0] += a[i] * w.x; acc[i][1] += a[i] * w.y;
                acc[i][2] += a[i] * w.z; acc[i][3] += a[i] * w.w;
            }
        }
        __syncthreads();
    }
    #pragma unroll
    for (int i = 0; i < 8; ++i) {
        int row = row0 + rid * 8 + i;
        if (row < N)
            ((float4*)C)[(size_t)row * 32 + cid] =
                make_float4(acc[i][0], acc[i][1], acc[i][2], acc[i][3]);
    }
}

// Per-node attention coefficients (one wave per node) + zero ssum.
__global__ __launch_bounds__(256) void att_node(const float* __restrict__ xlin,
                                                const float* __restrict__ att,
                                                float* __restrict__ a_src,
                                                float* __restrict__ a_dst,
                                                float* __restrict__ ssum, int N) {
    int n = blockIdx.x * 4 + (threadIdx.x >> 6);
    int l = threadIdx.x & 63;
    if (n >= N) return;
    float x0 = xlin[(size_t)n * 128 + l];
    float x1 = xlin[(size_t)n * 128 + 64 + l];
    float pd0 = x0 * att[l];        float ps0 = x0 * att[64 + l];
    float pd1 = x1 * att[128 + l];  float ps1 = x1 * att[192 + l];
    #pragma unroll
    for (int m = 32; m; m >>= 1) {
        pd0 += __shfl_xor(pd0, m);
        ps0 += __shfl_xor(ps0, m);
        pd1 += __shfl_xor(pd1, m);
        ps1 += __shfl_xor(ps1, m);
    }
    if (l == 0) {
        a_dst[n * 2 + 0] = pd0; a_dst[n * 2 + 1] = pd1;
        a_src[n * 2 + 0] = ps0; a_src[n * 2 + 1] = ps1;
        ssum[n * 2 + 0] = 0.f;  ssum[n * 2 + 1] = 0.f;
    }
}

// ------------------------- CSR-by-dst build (once) -------------------------
__global__ __launch_bounds__(256) void init_deg(unsigned int* __restrict__ deg, int N) {
    int n = blockIdx.x * 256 + threadIdx.x;
    if (n < N) deg[n] = 1u;  // self-loop
}

__global__ __launch_bounds__(256) void hist_dst(const int* __restrict__ ei, int E,
                                                unsigned int* __restrict__ deg) {
    int e = blockIdx.x * 256 + threadIdx.x;
    if (e < E) atomicAdd(&deg[ei[E + e]], 1u);
}

// Single-block exclusive scan; deg becomes the cursor (start offsets).
__global__ __launch_bounds__(1024) void scan_off(unsigned int* __restrict__ deg,
                                                 unsigned int* __restrict__ off, int N) {
    __shared__ unsigned int part[1024];
    int t = threadIdx.x;
    int chunk = (N + 1023) / 1024;
    int lo = t * chunk, hi = lo + chunk; if (hi > N) hi = N; if (lo > N) lo = N;
    unsigned int s = 0;
    for (int i = lo; i < hi; ++i) s += deg[i];
    part[t] = s;
    __syncthreads();
    for (int d = 1; d < 1024; d <<= 1) {
        unsigned int v = (t >= d) ? part[t - d] : 0u;
        __syncthreads();
        part[t] += v;
        __syncthreads();
    }
    unsigned int run = (t == 0) ? 0u : part[t - 1];
    for (int i = lo; i < hi; ++i) {
        unsigned int dv = deg[i];
        off[i] = run;
        deg[i] = run;   // cursor
        run += dv;
    }
    if (t == 1023) off[N] = part[1023];
}

// Scatter: record src per CSR slot, and CSR slot per edge.
__global__ __launch_bounds__(256) void scatter_dst(const int* __restrict__ ei, int E, int Et,
                                                   unsigned int* __restrict__ cur,
                                                   int* __restrict__ srcs,
                                                   unsigned int* __restrict__ pos) {
    int e = blockIdx.x * 256 + threadIdx.x;
    if (e >= Et) return;
    int s, d;
    if (e < E) { s = ei[e]; d = ei[E + e]; } else { s = d = e - E; }
    unsigned int p = atomicAdd(&cur[d], 1u);
    srcs[p] = s;
    pos[e] = p;
}

// ---- fused alpha + exp, scattered into CSR order + segment-sum (by src) ----
__global__ __launch_bounds__(256) void edge_ae(const int* __restrict__ ei, int E, int Et,
                                               const unsigned int* __restrict__ pos,
                                               const float* __restrict__ a_src,
                                               const float* __restrict__ a_dst,
                                               float* __restrict__ acsr,
                                               float* __restrict__ ssum) {
    int e = blockIdx.x * 256 + threadIdx.x;
    if (e >= Et) return;
    int s, d;
    if (e < E) { s = ei[e]; d = ei[E + e]; } else { s = d = e - E; }
    float2 ad = ((const float2*)a_dst)[d];
    float2 as = ((const float2*)a_src)[s];
    float al0 = ad.x + as.x; al0 = (al0 > 0.f) ? al0 : 0.2f * al0;
    float al1 = ad.y + as.y; al1 = (al1 > 0.f) ? al1 : 0.2f * al1;
    float e0 = __expf(al0), e1 = __expf(al1);
    ((float2*)acsr)[pos[e]] = make_float2(e0, e1);
    atomicAdd(&ssum[s * 2 + 0], e0);
    atomicAdd(&ssum[s * 2 + 1], e1);
}

// ssum -> 1/(ssum+eps), in place.
__global__ __launch_bounds__(256) void recip_node(float* __restrict__ ssum, int total) {
    int i = blockIdx.x * 256 + threadIdx.x;
    if (i < total) ssum[i] = 1.0f / (ssum[i] + 1e-16f);
}

// ---------------- CSR aggregation: one wave per dst node -------------------
// lane l covers features 2l,2l+1 (head = l>>5). Loop chain: srcs[j] (seq) ->
// {recip[s] (8B, L2) || xlin row (512B)}. Unroll-4 keeps 4 rows in flight.
// Fuses /ssum, +bias, relu; LAST also fuses out_proj + argmax.
template <bool LAST>
__global__ __launch_bounds__(256) void agg_csr(const int* __restrict__ srcs,
                                               const unsigned int* __restrict__ off,
                                               const float* __restrict__ xlin,
                                               const float* __restrict__ acsr,
                                               const float* __restrict__ rcp,
                                               const float* __restrict__ bias,
                                               float* __restrict__ out,
                                               const float* __restrict__ Wout,
                                               const float* __restrict__ bout,
                                               float* __restrict__ out3,
                                               float* __restrict__ ypred, int N) {
    int d = blockIdx.x * 4 + (threadIdx.x >> 6);
    int l = threadIdx.x & 63;
    if (d >= N) return;
    const int hh = l >> 5;  // head
    unsigned int j0 = off[d], j1 = off[d + 1];
    const float2* x2 = (const float2*)xlin;
    const float2* a2 = (const float2*)acsr;
    const float2* r2 = (const float2*)rcp;
    float accx = 0.f, accy = 0.f;
    unsigned int j = j0;
    for (; j + 4 <= j1; j += 4) {
        int s0 = srcs[j], s1 = srcs[j + 1], s2 = srcs[j + 2], s3 = srcs[j + 3];
        float2 al0 = a2[j], al1 = a2[j + 1], al2 = a2[j + 2], al3 = a2[j + 3];
        float2 rc0 = r2[s0], rc1 = r2[s1], rc2 = r2[s2], rc3 = r2[s3];
        float2 v0 = x2[(size_t)s0 * 64 + l];
        float2 v1 = x2[(size_t)s1 * 64 + l];
        float2 v2 = x2[(size_t)s2 * 64 + l];
        float2 v3 = x2[(size_t)s3 * 64 + l];
        float w0 = hh ? al0.y * rc0.y : al0.x * rc0.x;
        float w1 = hh ? al1.y * rc1.y : al1.x * rc1.x;
        float w2 = hh ? al2.y * rc2.y : al2.x * rc2.x;
        float w3 = hh ? al3.y * rc3.y : al3.x * rc3.x;
        accx += v0.x * w0 + v1.x * w1 + v2.x * w2 + v3.x * w3;
        accy += v0.y * w0 + v1.y * w1 + v2.y * w2 + v3.y * w3;
    }
    for (; j < j1; ++j) {
        int s = srcs[j];
        float2 al = a2[j];
        float2 rc = r2[s];
        float2 v = x2[(size_t)s * 64 + l];
        float w = hh ? al.y * rc.y : al.x * rc.x;
        accx += v.x * w;
        accy += v.y * w;
    }
    float2 bb = ((const float2*)bias)[l];
    float o0 = fmaxf(accx + bb.x, 0.f);
    float o1 = fmaxf(accy + bb.y, 0.f);
    ((float2*)out)[(size_t)d * 64 + l] = make_float2(o0, o1);
    if (LAST) {
        const float2* W2 = (const float2*)Wout;
        float2 wa = W2[l], wb = W2[64 + l], wc = W2[128 + l];
        float p0 = o0 * wa.x + o1 * wa.y;
        float p1 = o0 * wb.x + o1 * wb.y;
        float p2 = o0 * wc.x + o1 * wc.y;
        #pragma unroll
        for (int m = 32; m; m >>= 1) {
            p0 += __shfl_xor(p0, m);
            p1 += __shfl_xor(p1, m);
            p2 += __shfl_xor(p2, m);
        }
        if (l == 0) {
            p0 += bout[0]; p1 += bout[1]; p2 += bout[2];
            out3[d * 3 + 0] = p0; out3[d * 3 + 1] = p1; out3[d * 3 + 2] = p2;
            int am = 0; float best = p0;
            if (p1 > best) { best = p1; am = 1; }
            if (p2 > best) { best = p2; am = 2; }
            ypred[d] = (float)am;
        }
    }
}

__global__ __launch_bounds__(256) void gather_out(const float* __restrict__ out3,
                                                  const float* __restrict__ ypred,
                                                  const int* __restrict__ node_index,
                                                  float* __restrict__ node_out,
                                                  float* __restrict__ y_nodepred, int M) {
    int i = blockIdx.x * 256 + threadIdx.x;
    if (i >= M) return;
    int idx = node_index[i];
    node_out[i * 3 + 0] = out3[idx * 3 + 0];
    node_out[i * 3 + 1] = out3[idx * 3 + 1];
    node_out[i * 3 + 2] = out3[idx * 3 + 2];
    y_nodepred[i] = ypred[idx];
}

extern "C" void kernel_launch(void* const* d_in, const int* in_sizes, int n_in,
                              void* d_out, int out_size, void* d_ws, size_t ws_size,
                              hipStream_t stream) {
    const float* x          = (const float*)d_in[0];
    const int*   ei         = (const int*)d_in[1];
    const int*   node_index = (const int*)d_in[3];
    const float* W[3]   = {(const float*)d_in[4], (const float*)d_in[7], (const float*)d_in[10]};
    const float* att[3] = {(const float*)d_in[5], (const float*)d_in[8], (const float*)d_in[11]};
    const float* b[3]   = {(const float*)d_in[6], (const float*)d_in[9], (const float*)d_in[12]};
    const float* Wout = (const float*)d_in[13];
    const float* bout = (const float*)d_in[14];

    const int N  = in_sizes[0] / 128;
    const int E  = in_sizes[1] / 2;
    const int Et = E + N;
    const int M  = in_sizes[3];

    // workspace layout (floats), ~67 MB total
    float* ws     = (float*)d_ws;
    float* xlin   = ws;                               // N*128
    float* hb     = xlin + (size_t)N * 128;           // N*128
    float* a_src  = hb + (size_t)N * 128;             // N*2
    float* a_dst  = a_src + (size_t)N * 2;            // N*2
    float* ssum   = a_dst + (size_t)N * 2;            // N*2 (becomes recip)
    float* acsr   = ssum + (size_t)N * 2;             // Et*2 (exp(alpha) in CSR order)
    float* out3   = acsr + (size_t)Et * 2;            // N*3
    unsigned int* off  = (unsigned int*)(out3 + (size_t)N * 3 + 1);  // N+1
    unsigned int* deg  = off + (size_t)N + 4;          // N (scatter cursor)
    unsigned int* pos  = deg + (size_t)N;              // Et (CSR slot per edge)
    int*          srcs = (int*)(pos + (size_t)Et);     // Et (src per CSR slot)

    // output layout (floats): x_embed | node_output | ypred | y_nodepred
    float* o_embed = (float*)d_out;
    float* o_node  = o_embed + (size_t)N * 128;
    float* o_ypred = o_node + (size_t)M * 3;
    float* o_ynode = o_ypred + (size_t)N;

    const int gemm_blocks = (N + 63) / 64;
    const int node_wave_blocks = (N + 3) / 4;
    const int edge_blocks = (Et + 255) / 256;
    const int n_blocks = (N + 255) / 256;

    // ---- CSR by dst (built once, reused for all 3 layers) ----
    init_deg<<<n_blocks, 256, 0, stream>>>(deg, N);
    hist_dst<<<(E + 255) / 256, 256, 0, stream>>>(ei, E, deg);
    scan_off<<<1, 1024, 0, stream>>>(deg, off, N);
    scatter_dst<<<edge_blocks, 256, 0, stream>>>(ei, E, Et, deg, srcs, pos);

    for (int L = 0; L < 3; ++L) {
        const float* hin = (L == 0) ? x : hb;
        gemm128<<<gemm_blocks, 256, 0, stream>>>(hin, W[L], xlin, N);
        att_node<<<node_wave_blocks, 256, 0, stream>>>(xlin, att[L], a_src, a_dst, ssum, N);
        edge_ae<<<edge_blocks, 256, 0, stream>>>(ei, E, Et, pos, a_src, a_dst, acsr, ssum);
        recip_node<<<(2 * N + 255) / 256, 256, 0, stream>>>(ssum, 2 * N);
        if (L < 2)
            agg_csr<false><<<node_wave_blocks, 256, 0, stream>>>(
                srcs, off, xlin, acsr, ssum, b[L], hb, nullptr, nullptr, nullptr, nullptr, N);
        else
            agg_csr<true><<<node_wave_blocks, 256, 0, stream>>>(
                srcs, off, xlin, acsr, ssum, b[L], o_embed, Wout, bout, out3, o_ypred, N);
    }
    gather_out<<<(M + 255) / 256, 256, 0, stream>>>(out3, o_ypred, node_index, o_node, o_ynode, M);
}

// Round 4
// 726.712 us; speedup vs baseline: 2.3784x; 1.2299x over previous
//
#include <hip/hip_runtime.h>
#include <math.h>

// ---------------------------------------------------------------------------
// GAT forward (3 layers) on MI355X. f32. N=50000, D=128, H=2, k=64.
// E=800000 real edges + N self-loops (Et=850000).
// Round 4: hierarchical scan (was 110us single-block), scalarized agg loop
// (readfirstlane dst -> s_load for srcs/nodeinfo), packed {a_src,rcp} float4,
// exp recomputed in agg (acsr/pos arrays deleted), gemm float4 LDS reads.
// ---------------------------------------------------------------------------

// C = A(N x 128) @ W^T(128 x 128).  64-row tiles, W transposed into LDS.
__global__ __launch_bounds__(256) void gemm128(const float* __restrict__ A,
                                               const float* __restrict__ Wm,
                                               float* __restrict__ C, int N) {
    __shared__ float As[64][68];    // 68*4=272B row stride -> float4 aligned
    __shared__ float Wt[64][132];
    const int tx = threadIdx.x;
    const int row0 = blockIdx.x * 64;
    const int cid = tx & 31;
    const int rid = tx >> 5;
    float acc[8][4] = {};
    const float4* A4 = (const float4*)A;
    const float4* W4 = (const float4*)Wm;

    for (int kt = 0; kt < 2; ++kt) {
        for (int i = tx; i < 1024; i += 256) {
            int r = i >> 4, q = i & 15;
            int row = row0 + r;
            float4 v = (row < N) ? A4[(size_t)row * 32 + kt * 16 + q]
                                 : make_float4(0.f, 0.f, 0.f, 0.f);
            As[r][q * 4 + 0] = v.x; As[r][q * 4 + 1] = v.y;
            As[r][q * 4 + 2] = v.z; As[r][q * 4 + 3] = v.w;
        }
        for (int i = tx; i < 2048; i += 256) {
            int c = i >> 4, q = i & 15;
            float4 v = W4[(size_t)c * 32 + kt * 16 + q];
            Wt[q * 4 + 0][c] = v.x; Wt[q * 4 + 1][c] = v.y;
            Wt[q * 4 + 2][c] = v.z; Wt[q * 4 + 3][c] = v.w;
        }
        __syncthreads();
        for (int k = 0; k < 64; k += 4) {
            float4 a[8];
            #pragma unroll
            for (int i = 0; i < 8; ++i) a[i] = *(const float4*)&As[rid * 8 + i][k];
            #pragma unroll
            for (int kk = 0; kk < 4; ++kk) {
                float4 w = *(const float4*)&Wt[k + kk][cid * 4];
                #pragma unroll
                for (int i = 0; i < 8; ++i) {
                    float av = (kk == 0) ? a[i].x : (kk == 1) ? a[i].y : (kk == 2) ? a[i].z : a[i].w;
                    acc[i][0] += av * w.x; acc[i][1] += av * w.y;
                    acc[i][2] += av * w.z; acc[i][3] += av * w.w;
                }
            }
        }
        __syncthreads();
    }
    #pragma unroll
    for (int i = 0; i < 8; ++i) {
        int row = row0 + rid * 8 + i;
        if (row < N)
            ((float4*)C)[(size_t)row * 32 + cid] =
                make_float4(acc[i][0], acc[i][1], acc[i][2], acc[i][3]);
    }
}

// Per-node attention coefficients (one wave per node); packs a_src into
// nodeinfo.xy (zw filled by recip_node later); zeroes ssum.
__global__ __launch_bounds__(256) void att_node(const float* __restrict__ xlin,
                                                const float* __restrict__ att,
                                                float4* __restrict__ ni4,
                                                float2* __restrict__ ad2,
                                                float* __restrict__ ssum, int N) {
    int n = blockIdx.x * 4 + (threadIdx.x >> 6);
    int l = threadIdx.x & 63;
    if (n >= N) return;
    float x0 = xlin[(size_t)n * 128 + l];
    float x1 = xlin[(size_t)n * 128 + 64 + l];
    float pd0 = x0 * att[l];        float ps0 = x0 * att[64 + l];
    float pd1 = x1 * att[128 + l];  float ps1 = x1 * att[192 + l];
    #pragma unroll
    for (int m = 32; m; m >>= 1) {
        pd0 += __shfl_xor(pd0, m);
        ps0 += __shfl_xor(ps0, m);
        pd1 += __shfl_xor(pd1, m);
        ps1 += __shfl_xor(ps1, m);
    }
    if (l == 0) {
        ad2[n] = make_float2(pd0, pd1);
        ni4[n] = make_float4(ps0, ps1, 0.f, 0.f);
        ssum[n * 2 + 0] = 0.f; ssum[n * 2 + 1] = 0.f;
    }
}

// ------------------------- CSR-by-dst build (once) -------------------------
__global__ __launch_bounds__(256) void init_deg(unsigned int* __restrict__ deg, int N) {
    int n = blockIdx.x * 256 + threadIdx.x;
    if (n < N) deg[n] = 1u;  // self-loop
}

__global__ __launch_bounds__(256) void hist_dst(const int* __restrict__ ei, int E,
                                                unsigned int* __restrict__ deg) {
    int e = blockIdx.x * 256 + threadIdx.x;
    if (e < E) atomicAdd(&deg[ei[E + e]], 1u);
}

// Hierarchical exclusive scan. p1: per-block (1024 items) local scan + bsum.
__global__ __launch_bounds__(256) void scan_p1(const unsigned int* __restrict__ deg,
                                               unsigned int* __restrict__ off,
                                               unsigned int* __restrict__ bsum, int N) {
    __shared__ unsigned int sh[256];
    int t = threadIdx.x;
    int base = blockIdx.x * 1024 + t * 4;
    unsigned int v0 = 0, v1 = 0, v2 = 0, v3 = 0;
    if (base + 3 < N) {
        uint4 q = *(const uint4*)&deg[base];
        v0 = q.x; v1 = q.y; v2 = q.z; v3 = q.w;
    } else {
        if (base + 0 < N) v0 = deg[base + 0];
        if (base + 1 < N) v1 = deg[base + 1];
        if (base + 2 < N) v2 = deg[base + 2];
        if (base + 3 < N) v3 = deg[base + 3];
    }
    sh[t] = v0 + v1 + v2 + v3;
    __syncthreads();
    #pragma unroll
    for (int d = 1; d < 256; d <<= 1) {
        unsigned int u = (t >= d) ? sh[t - d] : 0u;
        __syncthreads();
        sh[t] += u;
        __syncthreads();
    }
    unsigned int ex = (t == 0) ? 0u : sh[t - 1];
    if (base + 3 < N) {
        *(uint4*)&off[base] = make_uint4(ex, ex + v0, ex + v0 + v1, ex + v0 + v1 + v2);
    } else {
        if (base + 0 < N) off[base + 0] = ex;
        if (base + 1 < N) off[base + 1] = ex + v0;
        if (base + 2 < N) off[base + 2] = ex + v0 + v1;
        if (base + 3 < N) off[base + 3] = ex + v0 + v1 + v2;
    }
    if (t == 255) bsum[blockIdx.x] = sh[255];
}

// p2: one block scans the (<=1024) block sums, exclusive, in place.
__global__ __launch_bounds__(1024) void scan_p2(unsigned int* __restrict__ bsum, int NB) {
    __shared__ unsigned int sh[1024];
    int t = threadIdx.x;
    sh[t] = (t < NB) ? bsum[t] : 0u;
    __syncthreads();
    #pragma unroll
    for (int d = 1; d < 1024; d <<= 1) {
        unsigned int u = (t >= d) ? sh[t - d] : 0u;
        __syncthreads();
        sh[t] += u;
        __syncthreads();
    }
    if (t < NB) bsum[t] = (t == 0) ? 0u : sh[t - 1];
}

// p3: off[i] += bsum[block]; cursor copy; off[N] = Et.
__global__ __launch_bounds__(256) void scan_p3(unsigned int* __restrict__ off,
                                               const unsigned int* __restrict__ bsum,
                                               unsigned int* __restrict__ cur,
                                               int N, unsigned int total) {
    int i = blockIdx.x * 256 + threadIdx.x;
    if (i < N) {
        unsigned int v = off[i] + bsum[i >> 10];
        off[i] = v;
        cur[i] = v;
    }
    if (i == N) off[N] = total;
}

__global__ __launch_bounds__(256) void scatter_dst(const int* __restrict__ ei, int E, int Et,
                                                   unsigned int* __restrict__ cur,
                                                   int* __restrict__ srcs) {
    int e = blockIdx.x * 256 + threadIdx.x;
    if (e >= Et) return;
    int s, d;
    if (e < E) { s = ei[e]; d = ei[E + e]; } else { s = d = e - E; }
    srcs[atomicAdd(&cur[d], 1u)] = s;
}

// -------------- per-edge exp + segment-sum by src (atomics) ----------------
__global__ __launch_bounds__(256) void edge_sum(const int* __restrict__ ei, int E, int Et,
                                                const float2* __restrict__ ad2,
                                                const float* __restrict__ ni,
                                                float* __restrict__ ssum) {
    int e = blockIdx.x * 256 + threadIdx.x;
    if (e >= Et) return;
    int s, d;
    if (e < E) { s = ei[e]; d = ei[E + e]; } else { s = d = e - E; }
    float2 ad = ad2[d];
    float2 as = *(const float2*)&ni[(size_t)s * 4];
    float al0 = ad.x + as.x; al0 = (al0 > 0.f) ? al0 : 0.2f * al0;
    float al1 = ad.y + as.y; al1 = (al1 > 0.f) ? al1 : 0.2f * al1;
    atomicAdd(&ssum[s * 2 + 0], __expf(al0));
    atomicAdd(&ssum[s * 2 + 1], __expf(al1));
}

// nodeinfo.zw = 1/(ssum+eps)
__global__ __launch_bounds__(256) void recip_node(const float* __restrict__ ssum,
                                                  float* __restrict__ ni, int N) {
    int n = blockIdx.x * 256 + threadIdx.x;
    if (n >= N) return;
    float2 s = ((const float2*)ssum)[n];
    ni[(size_t)n * 4 + 2] = 1.0f / (s.x + 1e-16f);
    ni[(size_t)n * 4 + 3] = 1.0f / (s.y + 1e-16f);
}

// ---------------- CSR aggregation: one wave per dst node -------------------
template <int U>
__device__ __forceinline__ void agg_edges(unsigned int j, const int* __restrict__ srcs,
                                          const float4* __restrict__ ni4,
                                          const float2* __restrict__ x2,
                                          float2 ad, int l, int hi,
                                          float& accx, float& accy) {
    int s[U]; float4 ni[U]; float2 v[U];
    #pragma unroll
    for (int u = 0; u < U; ++u) s[u] = srcs[j + u];
    #pragma unroll
    for (int u = 0; u < U; ++u) ni[u] = ni4[s[u]];
    #pragma unroll
    for (int u = 0; u < U; ++u) v[u] = x2[(size_t)s[u] * 64 + l];
    #pragma unroll
    for (int u = 0; u < U; ++u) {
        float al0 = ad.x + ni[u].x; al0 = (al0 > 0.f) ? al0 : 0.2f * al0;
        float al1 = ad.y + ni[u].y; al1 = (al1 > 0.f) ? al1 : 0.2f * al1;
        float w = hi ? __expf(al1) * ni[u].w : __expf(al0) * ni[u].z;
        accx += v[u].x * w;
        accy += v[u].y * w;
    }
}

template <bool LAST>
__global__ __launch_bounds__(256) void agg_csr(const int* __restrict__ srcs,
                                               const unsigned int* __restrict__ off,
                                               const float* __restrict__ xlin,
                                               const float4* __restrict__ ni4,
                                               const float2* __restrict__ ad2,
                                               const float* __restrict__ bias,
                                               float* __restrict__ out,
                                               const float* __restrict__ Wout,
                                               const float* __restrict__ bout,
                                               float* __restrict__ out3,
                                               float* __restrict__ ypred, int N) {
    int d = blockIdx.x * 4 + (threadIdx.x >> 6);
    int l = threadIdx.x & 63;
    if (d >= N) return;
    d = __builtin_amdgcn_readfirstlane(d);   // wave-uniform -> scalar loads
    const int hi = l >> 5;
    float2 ad = ad2[d];
    unsigned int j0 = off[d], j1 = off[d + 1];
    const float2* x2 = (const float2*)xlin;
    float accx = 0.f, accy = 0.f;
    unsigned int j = j0;
    for (; j + 8 <= j1; j += 8) agg_edges<8>(j, srcs, ni4, x2, ad, l, hi, accx, accy);
    if (j + 4 <= j1) { agg_edges<4>(j, srcs, ni4, x2, ad, l, hi, accx, accy); j += 4; }
    if (j + 2 <= j1) { agg_edges<2>(j, srcs, ni4, x2, ad, l, hi, accx, accy); j += 2; }
    if (j < j1)      { agg_edges<1>(j, srcs, ni4, x2, ad, l, hi, accx, accy); }

    float2 bb = ((const float2*)bias)[l];
    float o0 = fmaxf(accx + bb.x, 0.f);
    float o1 = fmaxf(accy + bb.y, 0.f);
    ((float2*)out)[(size_t)d * 64 + l] = make_float2(o0, o1);
    if (LAST) {
        const float2* W2 = (const float2*)Wout;
        float2 wa = W2[l], wb = W2[64 + l], wc = W2[128 + l];
        float p0 = o0 * wa.x + o1 * wa.y;
        float p1 = o0 * wb.x + o1 * wb.y;
        float p2 = o0 * wc.x + o1 * wc.y;
        #pragma unroll
        for (int m = 32; m; m >>= 1) {
            p0 += __shfl_xor(p0, m);
            p1 += __shfl_xor(p1, m);
            p2 += __shfl_xor(p2, m);
        }
        if (l == 0) {
            p0 += bout[0]; p1 += bout[1]; p2 += bout[2];
            out3[d * 3 + 0] = p0; out3[d * 3 + 1] = p1; out3[d * 3 + 2] = p2;
            int am = 0; float best = p0;
            if (p1 > best) { best = p1; am = 1; }
            if (p2 > best) { best = p2; am = 2; }
            ypred[d] = (float)am;
        }
    }
}

__global__ __launch_bounds__(256) void gather_out(const float* __restrict__ out3,
                                                  const float* __restrict__ ypred,
                                                  const int* __restrict__ node_index,
                                                  float* __restrict__ node_out,
                                                  float* __restrict__ y_nodepred, int M) {
    int i = blockIdx.x * 256 + threadIdx.x;
    if (i >= M) return;
    int idx = node_index[i];
    node_out[i * 3 + 0] = out3[idx * 3 + 0];
    node_out[i * 3 + 1] = out3[idx * 3 + 1];
    node_out[i * 3 + 2] = out3[idx * 3 + 2];
    y_nodepred[i] = ypred[idx];
}

extern "C" void kernel_launch(void* const* d_in, const int* in_sizes, int n_in,
                              void* d_out, int out_size, void* d_ws, size_t ws_size,
                              hipStream_t stream) {
    const float* x          = (const float*)d_in[0];
    const int*   ei         = (const int*)d_in[1];
    const int*   node_index = (const int*)d_in[3];
    const float* W[3]   = {(const float*)d_in[4], (const float*)d_in[7], (const float*)d_in[10]};
    const float* att[3] = {(const float*)d_in[5], (const float*)d_in[8], (const float*)d_in[11]};
    const float* b[3]   = {(const float*)d_in[6], (const float*)d_in[9], (const float*)d_in[12]};
    const float* Wout = (const float*)d_in[13];
    const float* bout = (const float*)d_in[14];

    const int N  = in_sizes[0] / 128;
    const int E  = in_sizes[1] / 2;
    const int Et = E + N;
    const int M  = in_sizes[3];
    const int NB = (N + 1023) / 1024;   // scan blocks (<=1024)

    // workspace layout (floats), ~58 MB
    float* ws     = (float*)d_ws;
    float* xlin   = ws;                               // N*128
    float* hb     = xlin + (size_t)N * 128;           // N*128
    float* ad     = hb + (size_t)N * 128;             // N*2  (a_dst)
    float* ssum   = ad + (size_t)N * 2;               // N*2
    float* ni     = ssum + (size_t)N * 2;             // N*4  {as0,as1,rcp0,rcp1}
    float* out3   = ni + (size_t)N * 4;               // N*3
    unsigned int* off  = (unsigned int*)(out3 + (size_t)N * 3 + 1);  // N+1
    unsigned int* deg  = off + (size_t)N + 4;          // N
    unsigned int* cur  = deg + (size_t)N;              // N (scatter cursor)
    unsigned int* bsum = cur + (size_t)N;              // NB (+pad)
    int*          srcs = (int*)(bsum + 1024);          // Et

    // output layout (floats): x_embed | node_output | ypred | y_nodepred
    float* o_embed = (float*)d_out;
    float* o_node  = o_embed + (size_t)N * 128;
    float* o_ypred = o_node + (size_t)M * 3;
    float* o_ynode = o_ypred + (size_t)N;

    const int gemm_blocks = (N + 63) / 64;
    const int node_wave_blocks = (N + 3) / 4;
    const int edge_blocks = (Et + 255) / 256;
    const int n_blocks = (N + 255) / 256;

    // ---- CSR by dst (built once, reused for all 3 layers) ----
    init_deg<<<n_blocks, 256, 0, stream>>>(deg, N);
    hist_dst<<<(E + 255) / 256, 256, 0, stream>>>(ei, E, deg);
    scan_p1<<<NB, 256, 0, stream>>>(deg, off, bsum, N);
    scan_p2<<<1, 1024, 0, stream>>>(bsum, NB);
    scan_p3<<<(N + 256) / 256, 256, 0, stream>>>(off, bsum, cur, N, (unsigned int)Et);
    scatter_dst<<<edge_blocks, 256, 0, stream>>>(ei, E, Et, cur, srcs);

    for (int L = 0; L < 3; ++L) {
        const float* hin = (L == 0) ? x : hb;
        gemm128<<<gemm_blocks, 256, 0, stream>>>(hin, W[L], xlin, N);
        att_node<<<node_wave_blocks, 256, 0, stream>>>(xlin, att[L], (float4*)ni, (float2*)ad,
                                                       ssum, N);
        edge_sum<<<edge_blocks, 256, 0, stream>>>(ei, E, Et, (const float2*)ad, ni, ssum);
        recip_node<<<n_blocks, 256, 0, stream>>>(ssum, ni, N);
        if (L < 2)
            agg_csr<false><<<node_wave_blocks, 256, 0, stream>>>(
                srcs, off, xlin, (const float4*)ni, (const float2*)ad, b[L], hb,
                nullptr, nullptr, nullptr, nullptr, N);
        else
            agg_csr<true><<<node_wave_blocks, 256, 0, stream>>>(
                srcs, off, xlin, (const float4*)ni, (const float2*)ad, b[L], o_embed,
                Wout, bout, out3, o_ypred, N);
    }
    gather_out<<<(M + 255) / 256, 256, 0, stream>>>(out3, o_ypred, node_index, o_node, o_ynode, M);
}

// Round 5
// 585.250 us; speedup vs baseline: 2.9533x; 1.2417x over previous
//
#include <hip/hip_runtime.h>
#include <math.h>

// ---------------------------------------------------------------------------
// GAT forward (3 layers) on MI355X. f32. N=50000, D=128, H=2, k=64.
// E=800000 real edges + N self-loops (Et=850000).
// Round 5: dual CSR (by dst for aggregation, by src for softmax denominator).
// edge_sum atomics + recip_node deleted -> thread-per-node src_sum gathers
// a_dst over out-edges and writes reciprocal into nodeinfo.zw directly.
// ---------------------------------------------------------------------------

// C = A(N x 128) @ W^T(128 x 128).  64-row tiles, W transposed into LDS.
__global__ __launch_bounds__(256) void gemm128(const float* __restrict__ A,
                                               const float* __restrict__ Wm,
                                               float* __restrict__ C, int N) {
    __shared__ float As[64][68];
    __shared__ float Wt[64][132];
    const int tx = threadIdx.x;
    const int row0 = blockIdx.x * 64;
    const int cid = tx & 31;
    const int rid = tx >> 5;
    float acc[8][4] = {};
    const float4* A4 = (const float4*)A;
    const float4* W4 = (const float4*)Wm;

    for (int kt = 0; kt < 2; ++kt) {
        for (int i = tx; i < 1024; i += 256) {
            int r = i >> 4, q = i & 15;
            int row = row0 + r;
            float4 v = (row < N) ? A4[(size_t)row * 32 + kt * 16 + q]
                                 : make_float4(0.f, 0.f, 0.f, 0.f);
            As[r][q * 4 + 0] = v.x; As[r][q * 4 + 1] = v.y;
            As[r][q * 4 + 2] = v.z; As[r][q * 4 + 3] = v.w;
        }
        for (int i = tx; i < 2048; i += 256) {
            int c = i >> 4, q = i & 15;
            float4 v = W4[(size_t)c * 32 + kt * 16 + q];
            Wt[q * 4 + 0][c] = v.x; Wt[q * 4 + 1][c] = v.y;
            Wt[q * 4 + 2][c] = v.z; Wt[q * 4 + 3][c] = v.w;
        }
        __syncthreads();
        for (int k = 0; k < 64; k += 4) {
            float4 a[8];
            #pragma unroll
            for (int i = 0; i < 8; ++i) a[i] = *(const float4*)&As[rid * 8 + i][k];
            #pragma unroll
            for (int kk = 0; kk < 4; ++kk) {
                float4 w = *(const float4*)&Wt[k + kk][cid * 4];
                #pragma unroll
                for (int i = 0; i < 8; ++i) {
                    float av = (kk == 0) ? a[i].x : (kk == 1) ? a[i].y : (kk == 2) ? a[i].z : a[i].w;
                    acc[i][0] += av * w.x; acc[i][1] += av * w.y;
                    acc[i][2] += av * w.z; acc[i][3] += av * w.w;
                }
            }
        }
        __syncthreads();
    }
    #pragma unroll
    for (int i = 0; i < 8; ++i) {
        int row = row0 + rid * 8 + i;
        if (row < N)
            ((float4*)C)[(size_t)row * 32 + cid] =
                make_float4(acc[i][0], acc[i][1], acc[i][2], acc[i][3]);
    }
}

// Per-node attention coefficients (one wave per node); packs a_src into
// nodeinfo.xy (zw filled by src_sum later).
__global__ __launch_bounds__(256) void att_node(const float* __restrict__ xlin,
                                                const float* __restrict__ att,
                                                float4* __restrict__ ni4,
                                                float2* __restrict__ ad2, int N) {
    int n = blockIdx.x * 4 + (threadIdx.x >> 6);
    int l = threadIdx.x & 63;
    if (n >= N) return;
    float x0 = xlin[(size_t)n * 128 + l];
    float x1 = xlin[(size_t)n * 128 + 64 + l];
    float pd0 = x0 * att[l];        float ps0 = x0 * att[64 + l];
    float pd1 = x1 * att[128 + l];  float ps1 = x1 * att[192 + l];
    #pragma unroll
    for (int m = 32; m; m >>= 1) {
        pd0 += __shfl_xor(pd0, m);
        ps0 += __shfl_xor(ps0, m);
        pd1 += __shfl_xor(pd1, m);
        ps1 += __shfl_xor(ps1, m);
    }
    if (l == 0) {
        ad2[n] = make_float2(pd0, pd1);
        ni4[n] = make_float4(ps0, ps1, 0.f, 0.f);
    }
}

// ---------------------- dual CSR build (once) ------------------------------
__global__ __launch_bounds__(256) void init_deg(unsigned int* __restrict__ dd,
                                                unsigned int* __restrict__ ds, int N) {
    int n = blockIdx.x * 256 + threadIdx.x;
    if (n < N) { dd[n] = 1u; ds[n] = 1u; }  // self-loop
}

__global__ __launch_bounds__(256) void hist_both(const int* __restrict__ ei, int E,
                                                 unsigned int* __restrict__ dd,
                                                 unsigned int* __restrict__ ds) {
    int e = blockIdx.x * 256 + threadIdx.x;
    if (e < E) {
        atomicAdd(&ds[ei[e]], 1u);
        atomicAdd(&dd[ei[E + e]], 1u);
    }
}

// Hierarchical exclusive scan. p1: per-block (1024 items) local scan + bsum.
__global__ __launch_bounds__(256) void scan_p1(const unsigned int* __restrict__ deg,
                                               unsigned int* __restrict__ off,
                                               unsigned int* __restrict__ bsum, int N) {
    __shared__ unsigned int sh[256];
    int t = threadIdx.x;
    int base = blockIdx.x * 1024 + t * 4;
    unsigned int v0 = 0, v1 = 0, v2 = 0, v3 = 0;
    if (base + 3 < N) {
        uint4 q = *(const uint4*)&deg[base];
        v0 = q.x; v1 = q.y; v2 = q.z; v3 = q.w;
    } else {
        if (base + 0 < N) v0 = deg[base + 0];
        if (base + 1 < N) v1 = deg[base + 1];
        if (base + 2 < N) v2 = deg[base + 2];
        if (base + 3 < N) v3 = deg[base + 3];
    }
    sh[t] = v0 + v1 + v2 + v3;
    __syncthreads();
    #pragma unroll
    for (int d = 1; d < 256; d <<= 1) {
        unsigned int u = (t >= d) ? sh[t - d] : 0u;
        __syncthreads();
        sh[t] += u;
        __syncthreads();
    }
    unsigned int ex = (t == 0) ? 0u : sh[t - 1];
    if (base + 3 < N) {
        *(uint4*)&off[base] = make_uint4(ex, ex + v0, ex + v0 + v1, ex + v0 + v1 + v2);
    } else {
        if (base + 0 < N) off[base + 0] = ex;
        if (base + 1 < N) off[base + 1] = ex + v0;
        if (base + 2 < N) off[base + 2] = ex + v0 + v1;
        if (base + 3 < N) off[base + 3] = ex + v0 + v1 + v2;
    }
    if (t == 255) bsum[blockIdx.x] = sh[255];
}

__global__ __launch_bounds__(1024) void scan_p2(unsigned int* __restrict__ bsum, int NB) {
    __shared__ unsigned int sh[1024];
    int t = threadIdx.x;
    sh[t] = (t < NB) ? bsum[t] : 0u;
    __syncthreads();
    #pragma unroll
    for (int d = 1; d < 1024; d <<= 1) {
        unsigned int u = (t >= d) ? sh[t - d] : 0u;
        __syncthreads();
        sh[t] += u;
        __syncthreads();
    }
    if (t < NB) bsum[t] = (t == 0) ? 0u : sh[t - 1];
}

__global__ __launch_bounds__(256) void scan_p3(unsigned int* __restrict__ off,
                                               const unsigned int* __restrict__ bsum,
                                               unsigned int* __restrict__ cur,
                                               int N, unsigned int total) {
    int i = blockIdx.x * 256 + threadIdx.x;
    if (i < N) {
        unsigned int v = off[i] + bsum[i >> 10];
        off[i] = v;
        cur[i] = v;
    }
    if (i == N) off[N] = total;
}

__global__ __launch_bounds__(256) void scatter_both(const int* __restrict__ ei, int E, int Et,
                                                    unsigned int* __restrict__ cur_d,
                                                    unsigned int* __restrict__ cur_s,
                                                    int* __restrict__ srcs,
                                                    int* __restrict__ dsts) {
    int e = blockIdx.x * 256 + threadIdx.x;
    if (e >= Et) return;
    int s, d;
    if (e < E) { s = ei[e]; d = ei[E + e]; } else { s = d = e - E; }
    srcs[atomicAdd(&cur_d[d], 1u)] = s;
    dsts[atomicAdd(&cur_s[s], 1u)] = d;
}

// ---- softmax denominator per src node: gather a_dst over out-edges --------
// thread per node; writes nodeinfo.zw = 1/(sum+eps). No atomics.
__global__ __launch_bounds__(256) void src_sum(const int* __restrict__ dsts,
                                               const unsigned int* __restrict__ off_s,
                                               const float2* __restrict__ ad2,
                                               float* __restrict__ ni, int N) {
    int n = blockIdx.x * 256 + threadIdx.x;
    if (n >= N) return;
    float as0 = ni[(size_t)n * 4 + 0];
    float as1 = ni[(size_t)n * 4 + 1];
    unsigned int j0 = off_s[n], j1 = off_s[n + 1];
    float s0 = 0.f, s1 = 0.f;
    unsigned int j = j0;
    for (; j + 4 <= j1; j += 4) {
        int d0 = dsts[j], d1 = dsts[j + 1], d2 = dsts[j + 2], d3 = dsts[j + 3];
        float2 a0 = ad2[d0], a1 = ad2[d1], a2 = ad2[d2], a3 = ad2[d3];
        float t;
        t = as0 + a0.x; t = (t > 0.f) ? t : 0.2f * t; s0 += __expf(t);
        t = as1 + a0.y; t = (t > 0.f) ? t : 0.2f * t; s1 += __expf(t);
        t = as0 + a1.x; t = (t > 0.f) ? t : 0.2f * t; s0 += __expf(t);
        t = as1 + a1.y; t = (t > 0.f) ? t : 0.2f * t; s1 += __expf(t);
        t = as0 + a2.x; t = (t > 0.f) ? t : 0.2f * t; s0 += __expf(t);
        t = as1 + a2.y; t = (t > 0.f) ? t : 0.2f * t; s1 += __expf(t);
        t = as0 + a3.x; t = (t > 0.f) ? t : 0.2f * t; s0 += __expf(t);
        t = as1 + a3.y; t = (t > 0.f) ? t : 0.2f * t; s1 += __expf(t);
    }
    for (; j < j1; ++j) {
        float2 a = ad2[dsts[j]];
        float t;
        t = as0 + a.x; t = (t > 0.f) ? t : 0.2f * t; s0 += __expf(t);
        t = as1 + a.y; t = (t > 0.f) ? t : 0.2f * t; s1 += __expf(t);
    }
    ni[(size_t)n * 4 + 2] = 1.0f / (s0 + 1e-16f);
    ni[(size_t)n * 4 + 3] = 1.0f / (s1 + 1e-16f);
}

// ---------------- CSR aggregation: one wave per dst node -------------------
template <int U>
__device__ __forceinline__ void agg_edges(unsigned int j, const int* __restrict__ srcs,
                                          const float4* __restrict__ ni4,
                                          const float2* __restrict__ x2,
                                          float2 ad, int l, int hi,
                                          float& accx, float& accy) {
    int s[U]; float4 ni[U]; float2 v[U];
    #pragma unroll
    for (int u = 0; u < U; ++u) s[u] = srcs[j + u];
    #pragma unroll
    for (int u = 0; u < U; ++u) ni[u] = ni4[s[u]];
    #pragma unroll
    for (int u = 0; u < U; ++u) v[u] = x2[(size_t)s[u] * 64 + l];
    #pragma unroll
    for (int u = 0; u < U; ++u) {
        float al0 = ad.x + ni[u].x; al0 = (al0 > 0.f) ? al0 : 0.2f * al0;
        float al1 = ad.y + ni[u].y; al1 = (al1 > 0.f) ? al1 : 0.2f * al1;
        float w = hi ? __expf(al1) * ni[u].w : __expf(al0) * ni[u].z;
        accx += v[u].x * w;
        accy += v[u].y * w;
    }
}

template <bool LAST>
__global__ __launch_bounds__(256) void agg_csr(const int* __restrict__ srcs,
                                               const unsigned int* __restrict__ off,
                                               const float* __restrict__ xlin,
                                               const float4* __restrict__ ni4,
                                               const float2* __restrict__ ad2,
                                               const float* __restrict__ bias,
                                               float* __restrict__ out,
                                               const float* __restrict__ Wout,
                                               const float* __restrict__ bout,
                                               float* __restrict__ out3,
                                               float* __restrict__ ypred, int N) {
    int d = blockIdx.x * 4 + (threadIdx.x >> 6);
    int l = threadIdx.x & 63;
    if (d >= N) return;
    d = __builtin_amdgcn_readfirstlane(d);   // wave-uniform -> scalar loads
    const int hi = l >> 5;
    float2 ad = ad2[d];
    unsigned int j0 = off[d], j1 = off[d + 1];
    const float2* x2 = (const float2*)xlin;
    float accx = 0.f, accy = 0.f;
    unsigned int j = j0;
    for (; j + 8 <= j1; j += 8) agg_edges<8>(j, srcs, ni4, x2, ad, l, hi, accx, accy);
    if (j + 4 <= j1) { agg_edges<4>(j, srcs, ni4, x2, ad, l, hi, accx, accy); j += 4; }
    if (j + 2 <= j1) { agg_edges<2>(j, srcs, ni4, x2, ad, l, hi, accx, accy); j += 2; }
    if (j < j1)      { agg_edges<1>(j, srcs, ni4, x2, ad, l, hi, accx, accy); }

    float2 bb = ((const float2*)bias)[l];
    float o0 = fmaxf(accx + bb.x, 0.f);
    float o1 = fmaxf(accy + bb.y, 0.f);
    ((float2*)out)[(size_t)d * 64 + l] = make_float2(o0, o1);
    if (LAST) {
        const float2* W2 = (const float2*)Wout;
        float2 wa = W2[l], wb = W2[64 + l], wc = W2[128 + l];
        float p0 = o0 * wa.x + o1 * wa.y;
        float p1 = o0 * wb.x + o1 * wb.y;
        float p2 = o0 * wc.x + o1 * wc.y;
        #pragma unroll
        for (int m = 32; m; m >>= 1) {
            p0 += __shfl_xor(p0, m);
            p1 += __shfl_xor(p1, m);
            p2 += __shfl_xor(p2, m);
        }
        if (l == 0) {
            p0 += bout[0]; p1 += bout[1]; p2 += bout[2];
            out3[d * 3 + 0] = p0; out3[d * 3 + 1] = p1; out3[d * 3 + 2] = p2;
            int am = 0; float best = p0;
            if (p1 > best) { best = p1; am = 1; }
            if (p2 > best) { best = p2; am = 2; }
            ypred[d] = (float)am;
        }
    }
}

__global__ __launch_bounds__(256) void gather_out(const float* __restrict__ out3,
                                                  const float* __restrict__ ypred,
                                                  const int* __restrict__ node_index,
                                                  float* __restrict__ node_out,
                                                  float* __restrict__ y_nodepred, int M) {
    int i = blockIdx.x * 256 + threadIdx.x;
    if (i >= M) return;
    int idx = node_index[i];
    node_out[i * 3 + 0] = out3[idx * 3 + 0];
    node_out[i * 3 + 1] = out3[idx * 3 + 1];
    node_out[i * 3 + 2] = out3[idx * 3 + 2];
    y_nodepred[i] = ypred[idx];
}

extern "C" void kernel_launch(void* const* d_in, const int* in_sizes, int n_in,
                              void* d_out, int out_size, void* d_ws, size_t ws_size,
                              hipStream_t stream) {
    const float* x          = (const float*)d_in[0];
    const int*   ei         = (const int*)d_in[1];
    const int*   node_index = (const int*)d_in[3];
    const float* W[3]   = {(const float*)d_in[4], (const float*)d_in[7], (const float*)d_in[10]};
    const float* att[3] = {(const float*)d_in[5], (const float*)d_in[8], (const float*)d_in[11]};
    const float* b[3]   = {(const float*)d_in[6], (const float*)d_in[9], (const float*)d_in[12]};
    const float* Wout = (const float*)d_in[13];
    const float* bout = (const float*)d_in[14];

    const int N  = in_sizes[0] / 128;
    const int E  = in_sizes[1] / 2;
    const int Et = E + N;
    const int M  = in_sizes[3];
    const int NB = (N + 1023) / 1024;   // scan blocks (<=1024)

    // workspace layout (floats), ~61 MB
    float* ws     = (float*)d_ws;
    float* xlin   = ws;                               // N*128
    float* hb     = xlin + (size_t)N * 128;           // N*128
    float* ad     = hb + (size_t)N * 128;             // N*2  (a_dst)
    float* ni     = ad + (size_t)N * 2;               // N*4  {as0,as1,rcp0,rcp1}
    float* out3   = ni + (size_t)N * 4;               // N*3
    unsigned int* off_d = (unsigned int*)(out3 + (size_t)N * 3 + 1);  // N+1
    unsigned int* off_s = off_d + (size_t)N + 4;       // N+1
    unsigned int* deg_d = off_s + (size_t)N + 4;       // N
    unsigned int* deg_s = deg_d + (size_t)N;           // N
    unsigned int* cur_d = deg_s + (size_t)N;           // N
    unsigned int* cur_s = cur_d + (size_t)N;           // N
    unsigned int* bsum_d = cur_s + (size_t)N;          // 1024
    unsigned int* bsum_s = bsum_d + 1024;              // 1024
    int* srcs = (int*)(bsum_s + 1024);                 // Et
    int* dsts = srcs + (size_t)Et;                     // Et

    // output layout (floats): x_embed | node_output | ypred | y_nodepred
    float* o_embed = (float*)d_out;
    float* o_node  = o_embed + (size_t)N * 128;
    float* o_ypred = o_node + (size_t)M * 3;
    float* o_ynode = o_ypred + (size_t)N;

    const int gemm_blocks = (N + 63) / 64;
    const int node_wave_blocks = (N + 3) / 4;
    const int edge_blocks = (Et + 255) / 256;
    const int n_blocks = (N + 255) / 256;

    // ---- dual CSR (built once, reused for all 3 layers) ----
    init_deg<<<n_blocks, 256, 0, stream>>>(deg_d, deg_s, N);
    hist_both<<<(E + 255) / 256, 256, 0, stream>>>(ei, E, deg_d, deg_s);
    scan_p1<<<NB, 256, 0, stream>>>(deg_d, off_d, bsum_d, N);
    scan_p1<<<NB, 256, 0, stream>>>(deg_s, off_s, bsum_s, N);
    scan_p2<<<1, 1024, 0, stream>>>(bsum_d, NB);
    scan_p2<<<1, 1024, 0, stream>>>(bsum_s, NB);
    scan_p3<<<(N + 256) / 256, 256, 0, stream>>>(off_d, bsum_d, cur_d, N, (unsigned int)Et);
    scan_p3<<<(N + 256) / 256, 256, 0, stream>>>(off_s, bsum_s, cur_s, N, (unsigned int)Et);
    scatter_both<<<edge_blocks, 256, 0, stream>>>(ei, E, Et, cur_d, cur_s, srcs, dsts);

    for (int L = 0; L < 3; ++L) {
        const float* hin = (L == 0) ? x : hb;
        gemm128<<<gemm_blocks, 256, 0, stream>>>(hin, W[L], xlin, N);
        att_node<<<node_wave_blocks, 256, 0, stream>>>(xlin, att[L], (float4*)ni, (float2*)ad, N);
        src_sum<<<n_blocks, 256, 0, stream>>>(dsts, off_s, (const float2*)ad, ni, N);
        if (L < 2)
            agg_csr<false><<<node_wave_blocks, 256, 0, stream>>>(
                srcs, off_d, xlin, (const float4*)ni, (const float2*)ad, b[L], hb,
                nullptr, nullptr, nullptr, nullptr, N);
        else
            agg_csr<true><<<node_wave_blocks, 256, 0, stream>>>(
                srcs, off_d, xlin, (const float4*)ni, (const float2*)ad, b[L], o_embed,
                Wout, bout, out3, o_ypred, N);
    }
    gather_out<<<(M + 255) / 256, 256, 0, stream>>>(out3, o_ypred, node_index, o_node, o_ynode, M);
}

// Round 7
// 478.488 us; speedup vs baseline: 3.6122x; 1.2231x over previous
//
#include <hip/hip_runtime.h>
#include <math.h>

// ---------------------------------------------------------------------------
// GAT forward (3 layers) on MI355X. f32. N=50000, D=128, H=2, k=64.
// E=800000 real edges + N self-loops (Et=850000).
// Round 7: revert xlin to f32 (fp16 flipped >=1 argmax vs f32 reference);
// KEEP round-6 wins: 2-level MSD bucket-sort CSR build (no atomic-return
// storm, write-local) and att-dot fusion into the gemm epilogue.
// ---------------------------------------------------------------------------

#define EPB 8192   // edges per coarse-scatter block

// C = A(N x 128) @ W^T(128 x 128), f32. Epilogue computes the per-node
// attention dots from acc registers (a_dst -> ad2, a_src -> ni.xy).
__global__ __launch_bounds__(256) void gemm128(const float* __restrict__ A,
                                               const float* __restrict__ Wm,
                                               const float* __restrict__ att,
                                               float* __restrict__ C,
                                               float4* __restrict__ ni4,
                                               float2* __restrict__ ad2v, int N) {
    __shared__ float As[64][68];
    __shared__ float Wt[64][132];
    const int tx = threadIdx.x;
    const int row0 = blockIdx.x * 64;
    const int cid = tx & 31;
    const int rid = tx >> 5;
    float acc[8][4] = {};
    const float4* A4 = (const float4*)A;
    const float4* W4 = (const float4*)Wm;

    for (int kt = 0; kt < 2; ++kt) {
        for (int i = tx; i < 1024; i += 256) {
            int r = i >> 4, q = i & 15;
            int row = row0 + r;
            float4 v = (row < N) ? A4[(size_t)row * 32 + kt * 16 + q]
                                 : make_float4(0.f, 0.f, 0.f, 0.f);
            As[r][q * 4 + 0] = v.x; As[r][q * 4 + 1] = v.y;
            As[r][q * 4 + 2] = v.z; As[r][q * 4 + 3] = v.w;
        }
        for (int i = tx; i < 2048; i += 256) {
            int c = i >> 4, q = i & 15;
            float4 v = W4[(size_t)c * 32 + kt * 16 + q];
            Wt[q * 4 + 0][c] = v.x; Wt[q * 4 + 1][c] = v.y;
            Wt[q * 4 + 2][c] = v.z; Wt[q * 4 + 3][c] = v.w;
        }
        __syncthreads();
        for (int k = 0; k < 64; k += 4) {
            float4 a[8];
            #pragma unroll
            for (int i = 0; i < 8; ++i) a[i] = *(const float4*)&As[rid * 8 + i][k];
            #pragma unroll
            for (int kk = 0; kk < 4; ++kk) {
                float4 w = *(const float4*)&Wt[k + kk][cid * 4];
                #pragma unroll
                for (int i = 0; i < 8; ++i) {
                    float av = (kk == 0) ? a[i].x : (kk == 1) ? a[i].y : (kk == 2) ? a[i].z : a[i].w;
                    acc[i][0] += av * w.x; acc[i][1] += av * w.y;
                    acc[i][2] += av * w.z; acc[i][3] += av * w.w;
                }
            }
        }
        __syncthreads();
    }
    #pragma unroll
    for (int i = 0; i < 8; ++i) {
        int row = row0 + rid * 8 + i;
        if (row < N)
            ((float4*)C)[(size_t)row * 32 + cid] =
                make_float4(acc[i][0], acc[i][1], acc[i][2], acc[i][3]);
    }
    // fused attention dots: thread covers cols cid*4..cid*4+3 of head hh
    const int hh = cid >> 4;
    const int c0 = (cid & 15) * 4;
    float ad0 = att[hh * 128 + c0 + 0], ad1 = att[hh * 128 + c0 + 1];
    float ad2c = att[hh * 128 + c0 + 2], ad3 = att[hh * 128 + c0 + 3];
    float as0 = att[hh * 128 + 64 + c0 + 0], as1 = att[hh * 128 + 64 + c0 + 1];
    float as2 = att[hh * 128 + 64 + c0 + 2], as3 = att[hh * 128 + 64 + c0 + 3];
    float pd[8], ps[8];
    #pragma unroll
    for (int i = 0; i < 8; ++i) {
        pd[i] = acc[i][0] * ad0 + acc[i][1] * ad1 + acc[i][2] * ad2c + acc[i][3] * ad3;
        ps[i] = acc[i][0] * as0 + acc[i][1] * as1 + acc[i][2] * as2 + acc[i][3] * as3;
    }
    #pragma unroll
    for (int m = 1; m < 16; m <<= 1) {
        #pragma unroll
        for (int i = 0; i < 8; ++i) {
            pd[i] += __shfl_xor(pd[i], m);
            ps[i] += __shfl_xor(ps[i], m);
        }
    }
    const int ll = tx & 63;
    const int grp = ll & 32;
    #pragma unroll
    for (int i = 0; i < 8; ++i) {
        float d0 = __shfl(pd[i], grp + 0);
        float d1 = __shfl(pd[i], grp + 16);
        float s0 = __shfl(ps[i], grp + 0);
        float s1 = __shfl(ps[i], grp + 16);
        if ((ll & 31) == 0) {
            int row = row0 + rid * 8 + i;
            if (row < N) {
                ad2v[row] = make_float2(d0, d1);
                ni4[row] = make_float4(s0, s1, 0.f, 0.f);
            }
        }
    }
}

// ---------------------- dual CSR build (once) ------------------------------
__global__ __launch_bounds__(256) void init_deg(unsigned int* __restrict__ dd,
                                                unsigned int* __restrict__ ds, int N) {
    int n = blockIdx.x * 256 + threadIdx.x;
    if (n < N) { dd[n] = 1u; ds[n] = 1u; }  // self-loop
}

__global__ __launch_bounds__(256) void hist_both(const int* __restrict__ ei, int E,
                                                 unsigned int* __restrict__ dd,
                                                 unsigned int* __restrict__ ds) {
    int e = blockIdx.x * 256 + threadIdx.x;
    if (e < E) {
        atomicAdd(&ds[ei[e]], 1u);
        atomicAdd(&dd[ei[E + e]], 1u);
    }
}

__global__ __launch_bounds__(256) void scan_p1(const unsigned int* __restrict__ deg,
                                               unsigned int* __restrict__ off,
                                               unsigned int* __restrict__ bsum, int N) {
    __shared__ unsigned int sh[256];
    int t = threadIdx.x;
    int base = blockIdx.x * 1024 + t * 4;
    unsigned int v0 = 0, v1 = 0, v2 = 0, v3 = 0;
    if (base + 3 < N) {
        uint4 q = *(const uint4*)&deg[base];
        v0 = q.x; v1 = q.y; v2 = q.z; v3 = q.w;
    } else {
        if (base + 0 < N) v0 = deg[base + 0];
        if (base + 1 < N) v1 = deg[base + 1];
        if (base + 2 < N) v2 = deg[base + 2];
        if (base + 3 < N) v3 = deg[base + 3];
    }
    sh[t] = v0 + v1 + v2 + v3;
    __syncthreads();
    #pragma unroll
    for (int d = 1; d < 256; d <<= 1) {
        unsigned int u = (t >= d) ? sh[t - d] : 0u;
        __syncthreads();
        sh[t] += u;
        __syncthreads();
    }
    unsigned int ex = (t == 0) ? 0u : sh[t - 1];
    if (base + 3 < N) {
        *(uint4*)&off[base] = make_uint4(ex, ex + v0, ex + v0 + v1, ex + v0 + v1 + v2);
    } else {
        if (base + 0 < N) off[base + 0] = ex;
        if (base + 1 < N) off[base + 1] = ex + v0;
        if (base + 2 < N) off[base + 2] = ex + v0 + v1;
        if (base + 3 < N) off[base + 3] = ex + v0 + v1 + v2;
    }
    if (t == 255) bsum[blockIdx.x] = sh[255];
}

__global__ __launch_bounds__(1024) void scan_p2(unsigned int* __restrict__ bsum, int NB) {
    __shared__ unsigned int sh[1024];
    int t = threadIdx.x;
    sh[t] = (t < NB) ? bsum[t] : 0u;
    __syncthreads();
    #pragma unroll
    for (int d = 1; d < 1024; d <<= 1) {
        unsigned int u = (t >= d) ? sh[t - d] : 0u;
        __syncthreads();
        sh[t] += u;
        __syncthreads();
    }
    if (t < NB) bsum[t] = (t == 0) ? 0u : sh[t - 1];
}

__global__ __launch_bounds__(256) void scan_p3(unsigned int* __restrict__ off,
                                               const unsigned int* __restrict__ bsum,
                                               int N, unsigned int total) {
    int i = blockIdx.x * 256 + threadIdx.x;
    if (i < N) off[i] += bsum[i >> 10];
    if (i == N) off[N] = total;
}

// coarse-bucket cursors seeded from node offsets (bucket b = nodes b*64..)
__global__ __launch_bounds__(256) void init_cur(const unsigned int* __restrict__ off_d,
                                                const unsigned int* __restrict__ off_s,
                                                unsigned int* __restrict__ cur_d,
                                                unsigned int* __restrict__ cur_s, int CB) {
    int b = blockIdx.x * 256 + threadIdx.x;
    if (b < CB) { cur_d[b] = off_d[b * 64]; cur_s[b] = off_s[b * 64]; }
}

// MSD pass 1: bucket edges by key>>6 into block-reserved contiguous runs.
template <bool BYDST>
__global__ __launch_bounds__(512) void coarse_scatter(const int* __restrict__ ei, int E, int Et,
                                                      unsigned int* __restrict__ cur,
                                                      unsigned int* __restrict__ tmp, int CB) {
    __shared__ unsigned int lh[800];
    const int t = threadIdx.x;
    for (int b = t; b < CB; b += 512) lh[b] = 0u;
    __syncthreads();
    const int i0 = blockIdx.x * EPB;
    for (int i = t; i < EPB; i += 512) {
        int e = i0 + i;
        if (e < Et) {
            int k = (e < E) ? ei[BYDST ? (E + e) : e] : (e - E);
            atomicAdd(&lh[k >> 6], 1u);
        }
    }
    __syncthreads();
    for (int b = t; b < CB; b += 512) {
        unsigned int c = lh[b];
        lh[b] = atomicAdd(&cur[b], c);   // reserve contiguous run; becomes cursor
    }
    __syncthreads();
    for (int i = t; i < EPB; i += 512) {
        int e = i0 + i;
        if (e < Et) {
            int s, d;
            if (e < E) { s = ei[e]; d = ei[E + e]; } else { s = d = e - E; }
            int k = BYDST ? d : s;
            int v = BYDST ? s : d;
            unsigned int pos = atomicAdd(&lh[k >> 6], 1u);
            tmp[pos] = ((unsigned int)(k & 63) << 16) | (unsigned int)v;
        }
    }
}

// MSD pass 2: one block per 64-node bucket; LDS cursors = global off values.
__global__ __launch_bounds__(256) void fine_sort(const unsigned int* __restrict__ tmp,
                                                 const unsigned int* __restrict__ off,
                                                 int* __restrict__ outv, int N) {
    __shared__ unsigned int h[64];
    const int b = blockIdx.x;
    const int node0 = b * 64;
    int nn = N - node0; if (nn > 64) nn = 64;
    const int t = threadIdx.x;
    if (t < nn) h[t] = off[node0 + t];
    __syncthreads();
    unsigned int base = off[node0];
    unsigned int end = off[node0 + nn];
    for (unsigned int i = base + t; i < end; i += 256) {
        unsigned int v = tmp[i];
        unsigned int pos = atomicAdd(&h[v >> 16], 1u);
        outv[pos] = (int)(v & 0xFFFFu);
    }
}

// ---- softmax denominator per src node: gather a_dst over out-edges --------
__global__ __launch_bounds__(256) void src_sum(const int* __restrict__ dsts,
                                               const unsigned int* __restrict__ off_s,
                                               const float2* __restrict__ ad2,
                                               float* __restrict__ ni, int N) {
    int n = blockIdx.x * 256 + threadIdx.x;
    if (n >= N) return;
    float as0 = ni[(size_t)n * 4 + 0];
    float as1 = ni[(size_t)n * 4 + 1];
    unsigned int j0 = off_s[n], j1 = off_s[n + 1];
    float s0 = 0.f, s1 = 0.f;
    unsigned int j = j0;
    for (; j + 4 <= j1; j += 4) {
        int d0 = dsts[j], d1 = dsts[j + 1], d2 = dsts[j + 2], d3 = dsts[j + 3];
        float2 a0 = ad2[d0], a1 = ad2[d1], a2 = ad2[d2], a3 = ad2[d3];
        float t;
        t = as0 + a0.x; t = (t > 0.f) ? t : 0.2f * t; s0 += __expf(t);
        t = as1 + a0.y; t = (t > 0.f) ? t : 0.2f * t; s1 += __expf(t);
        t = as0 + a1.x; t = (t > 0.f) ? t : 0.2f * t; s0 += __expf(t);
        t = as1 + a1.y; t = (t > 0.f) ? t : 0.2f * t; s1 += __expf(t);
        t = as0 + a2.x; t = (t > 0.f) ? t : 0.2f * t; s0 += __expf(t);
        t = as1 + a2.y; t = (t > 0.f) ? t : 0.2f * t; s1 += __expf(t);
        t = as0 + a3.x; t = (t > 0.f) ? t : 0.2f * t; s0 += __expf(t);
        t = as1 + a3.y; t = (t > 0.f) ? t : 0.2f * t; s1 += __expf(t);
    }
    for (; j < j1; ++j) {
        float2 a = ad2[dsts[j]];
        float t;
        t = as0 + a.x; t = (t > 0.f) ? t : 0.2f * t; s0 += __expf(t);
        t = as1 + a.y; t = (t > 0.f) ? t : 0.2f * t; s1 += __expf(t);
    }
    ni[(size_t)n * 4 + 2] = 1.0f / (s0 + 1e-16f);
    ni[(size_t)n * 4 + 3] = 1.0f / (s1 + 1e-16f);
}

// ---------------- CSR aggregation: one wave per dst node -------------------
template <int U>
__device__ __forceinline__ void agg_edges(unsigned int j, const int* __restrict__ srcs,
                                          const float4* __restrict__ ni4,
                                          const float2* __restrict__ x2,
                                          float2 ad, int l, int hi,
                                          float& accx, float& accy) {
    int s[U]; float4 ni[U]; float2 v[U];
    #pragma unroll
    for (int u = 0; u < U; ++u) s[u] = srcs[j + u];
    #pragma unroll
    for (int u = 0; u < U; ++u) ni[u] = ni4[s[u]];
    #pragma unroll
    for (int u = 0; u < U; ++u) v[u] = x2[(size_t)s[u] * 64 + l];
    #pragma unroll
    for (int u = 0; u < U; ++u) {
        float al0 = ad.x + ni[u].x; al0 = (al0 > 0.f) ? al0 : 0.2f * al0;
        float al1 = ad.y + ni[u].y; al1 = (al1 > 0.f) ? al1 : 0.2f * al1;
        float w = hi ? __expf(al1) * ni[u].w : __expf(al0) * ni[u].z;
        accx += v[u].x * w;
        accy += v[u].y * w;
    }
}

template <bool LAST>
__global__ __launch_bounds__(256) void agg_csr(const int* __restrict__ srcs,
                                               const unsigned int* __restrict__ off,
                                               const float2* __restrict__ x2,
                                               const float4* __restrict__ ni4,
                                               const float2* __restrict__ ad2,
                                               const float* __restrict__ bias,
                                               float* __restrict__ out,
                                               const float* __restrict__ Wout,
                                               const float* __restrict__ bout,
                                               float* __restrict__ out3,
                                               float* __restrict__ ypred, int N) {
    int d = blockIdx.x * 4 + (threadIdx.x >> 6);
    int l = threadIdx.x & 63;
    if (d >= N) return;
    d = __builtin_amdgcn_readfirstlane(d);   // wave-uniform -> scalar loads
    const int hi = l >> 5;
    float2 ad = ad2[d];
    unsigned int j0 = off[d], j1 = off[d + 1];
    float accx = 0.f, accy = 0.f;
    unsigned int j = j0;
    for (; j + 8 <= j1; j += 8) agg_edges<8>(j, srcs, ni4, x2, ad, l, hi, accx, accy);
    if (j + 4 <= j1) { agg_edges<4>(j, srcs, ni4, x2, ad, l, hi, accx, accy); j += 4; }
    if (j + 2 <= j1) { agg_edges<2>(j, srcs, ni4, x2, ad, l, hi, accx, accy); j += 2; }
    if (j < j1)      { agg_edges<1>(j, srcs, ni4, x2, ad, l, hi, accx, accy); }

    float2 bb = ((const float2*)bias)[l];
    float o0 = fmaxf(accx + bb.x, 0.f);
    float o1 = fmaxf(accy + bb.y, 0.f);
    ((float2*)out)[(size_t)d * 64 + l] = make_float2(o0, o1);
    if (LAST) {
        const float2* W2 = (const float2*)Wout;
        float2 wa = W2[l], wb = W2[64 + l], wc = W2[128 + l];
        float p0 = o0 * wa.x + o1 * wa.y;
        float p1 = o0 * wb.x + o1 * wb.y;
        float p2 = o0 * wc.x + o1 * wc.y;
        #pragma unroll
        for (int m = 32; m; m >>= 1) {
            p0 += __shfl_xor(p0, m);
            p1 += __shfl_xor(p1, m);
            p2 += __shfl_xor(p2, m);
        }
        if (l == 0) {
            p0 += bout[0]; p1 += bout[1]; p2 += bout[2];
            out3[d * 3 + 0] = p0; out3[d * 3 + 1] = p1; out3[d * 3 + 2] = p2;
            int am = 0; float best = p0;
            if (p1 > best) { best = p1; am = 1; }
            if (p2 > best) { best = p2; am = 2; }
            ypred[d] = (float)am;
        }
    }
}

__global__ __launch_bounds__(256) void gather_out(const float* __restrict__ out3,
                                                  const float* __restrict__ ypred,
                                                  const int* __restrict__ node_index,
                                                  float* __restrict__ node_out,
                                                  float* __restrict__ y_nodepred, int M) {
    int i = blockIdx.x * 256 + threadIdx.x;
    if (i >= M) return;
    int idx = node_index[i];
    node_out[i * 3 + 0] = out3[idx * 3 + 0];
    node_out[i * 3 + 1] = out3[idx * 3 + 1];
    node_out[i * 3 + 2] = out3[idx * 3 + 2];
    y_nodepred[i] = ypred[idx];
}

extern "C" void kernel_launch(void* const* d_in, const int* in_sizes, int n_in,
                              void* d_out, int out_size, void* d_ws, size_t ws_size,
                              hipStream_t stream) {
    const float* x          = (const float*)d_in[0];
    const int*   ei         = (const int*)d_in[1];
    const int*   node_index = (const int*)d_in[3];
    const float* W[3]   = {(const float*)d_in[4], (const float*)d_in[7], (const float*)d_in[10]};
    const float* att[3] = {(const float*)d_in[5], (const float*)d_in[8], (const float*)d_in[11]};
    const float* b[3]   = {(const float*)d_in[6], (const float*)d_in[9], (const float*)d_in[12]};
    const float* Wout = (const float*)d_in[13];
    const float* bout = (const float*)d_in[14];

    const int N  = in_sizes[0] / 128;
    const int E  = in_sizes[1] / 2;
    const int Et = E + N;
    const int M  = in_sizes[3];
    const int NB = (N + 1023) / 1024;        // scan blocks
    const int CB = (N + 63) / 64;            // coarse buckets
    const int NBLK = (Et + EPB - 1) / EPB;   // coarse scatter blocks

    // workspace layout (floats), ~64 MB
    float* ws     = (float*)d_ws;
    float* xlin   = ws;                               // N*128
    float* hb     = xlin + (size_t)N * 128;           // N*128
    float* ad     = hb + (size_t)N * 128;             // N*2  (a_dst)
    float* ni     = ad + (size_t)N * 2;               // N*4  {as0,as1,rcp0,rcp1}
    float* out3   = ni + (size_t)N * 4;               // N*3 (+pad)
    unsigned int* off_d = (unsigned int*)(out3 + (size_t)N * 3 + 4);  // N+4
    unsigned int* off_s = off_d + (size_t)N + 4;       // N+4
    unsigned int* deg_d = off_s + (size_t)N + 4;       // N
    unsigned int* deg_s = deg_d + (size_t)N;           // N
    unsigned int* cur_d = deg_s + (size_t)N;           // CB (pad 1024)
    unsigned int* cur_s = cur_d + 1024;                // CB (pad 1024)
    unsigned int* bsum_d = cur_s + 1024;               // NB (pad 1024)
    unsigned int* bsum_s = bsum_d + 1024;              // NB (pad 1024)
    int* srcs = (int*)(bsum_s + 1024);                 // Et
    int* dsts = srcs + (size_t)Et;                     // Et
    unsigned int* tmp = (unsigned int*)(dsts + (size_t)Et);  // Et (shared by both sorts)

    // output layout (floats): x_embed | node_output | ypred | y_nodepred
    float* o_embed = (float*)d_out;
    float* o_node  = o_embed + (size_t)N * 128;
    float* o_ypred = o_node + (size_t)M * 3;
    float* o_ynode = o_ypred + (size_t)N;

    const int gemm_blocks = (N + 63) / 64;
    const int node_wave_blocks = (N + 3) / 4;
    const int n_blocks = (N + 255) / 256;

    // ---- dual CSR via 2-level MSD bucket sort (built once) ----
    init_deg<<<n_blocks, 256, 0, stream>>>(deg_d, deg_s, N);
    hist_both<<<(E + 255) / 256, 256, 0, stream>>>(ei, E, deg_d, deg_s);
    scan_p1<<<NB, 256, 0, stream>>>(deg_d, off_d, bsum_d, N);
    scan_p1<<<NB, 256, 0, stream>>>(deg_s, off_s, bsum_s, N);
    scan_p2<<<1, 1024, 0, stream>>>(bsum_d, NB);
    scan_p2<<<1, 1024, 0, stream>>>(bsum_s, NB);
    scan_p3<<<(N + 256) / 256, 256, 0, stream>>>(off_d, bsum_d, N, (unsigned int)Et);
    scan_p3<<<(N + 256) / 256, 256, 0, stream>>>(off_s, bsum_s, N, (unsigned int)Et);
    init_cur<<<(CB + 255) / 256, 256, 0, stream>>>(off_d, off_s, cur_d, cur_s, CB);
    coarse_scatter<true><<<NBLK, 512, 0, stream>>>(ei, E, Et, cur_d, tmp, CB);
    fine_sort<<<CB, 256, 0, stream>>>(tmp, off_d, srcs, N);
    coarse_scatter<false><<<NBLK, 512, 0, stream>>>(ei, E, Et, cur_s, tmp, CB);
    fine_sort<<<CB, 256, 0, stream>>>(tmp, off_s, dsts, N);

    for (int L = 0; L < 3; ++L) {
        const float* hin = (L == 0) ? x : hb;
        gemm128<<<gemm_blocks, 256, 0, stream>>>(hin, W[L], att[L], xlin,
                                                 (float4*)ni, (float2*)ad, N);
        src_sum<<<n_blocks, 256, 0, stream>>>(dsts, off_s, (const float2*)ad, ni, N);
        if (L < 2)
            agg_csr<false><<<node_wave_blocks, 256, 0, stream>>>(
                srcs, off_d, (const float2*)xlin, (const float4*)ni, (const float2*)ad,
                b[L], hb, nullptr, nullptr, nullptr, nullptr, N);
        else
            agg_csr<true><<<node_wave_blocks, 256, 0, stream>>>(
                srcs, off_d, (const float2*)xlin, (const float4*)ni, (const float2*)ad,
                b[L], o_embed, Wout, bout, out3, o_ypred, N);
    }
    gather_out<<<(M + 255) / 256, 256, 0, stream>>>(out3, o_ypred, node_index, o_node, o_ynode, M);
}

// Round 8
// 471.705 us; speedup vs baseline: 3.6642x; 1.0144x over previous
//
#include <hip/hip_runtime.h>
#include <math.h>

// ---------------------------------------------------------------------------
// GAT forward (3 layers) on MI355X. f32. N=50000, D=128, H=2, k=64.
// E=800000 real edges + N self-loops (Et=850000).
// Round 8: per-edge weights precomputed once (edge_w, LDS binary-search for
// dst) -> agg_csr is pure streamed-weight + xlin row gather + FMA.
// CSR build: memset+scan-folded self-loops, dual-grid scans, EPB 4096.
// tmp aliases xlin; out3 aliases ad/ni (liveness-checked).
// ---------------------------------------------------------------------------

#define EPB 4096   // edges per coarse-scatter block

// C = A(N x 128) @ W^T(128 x 128), f32. Epilogue computes the per-node
// attention dots from acc registers (a_dst -> ad2, a_src -> ni.xy).
__global__ __launch_bounds__(256) void gemm128(const float* __restrict__ A,
                                               const float* __restrict__ Wm,
                                               const float* __restrict__ att,
                                               float* __restrict__ C,
                                               float4* __restrict__ ni4,
                                               float2* __restrict__ ad2v, int N) {
    __shared__ float As[64][68];
    __shared__ float Wt[64][132];
    const int tx = threadIdx.x;
    const int row0 = blockIdx.x * 64;
    const int cid = tx & 31;
    const int rid = tx >> 5;
    float acc[8][4] = {};
    const float4* A4 = (const float4*)A;
    const float4* W4 = (const float4*)Wm;

    for (int kt = 0; kt < 2; ++kt) {
        for (int i = tx; i < 1024; i += 256) {
            int r = i >> 4, q = i & 15;
            int row = row0 + r;
            float4 v = (row < N) ? A4[(size_t)row * 32 + kt * 16 + q]
                                 : make_float4(0.f, 0.f, 0.f, 0.f);
            As[r][q * 4 + 0] = v.x; As[r][q * 4 + 1] = v.y;
            As[r][q * 4 + 2] = v.z; As[r][q * 4 + 3] = v.w;
        }
        for (int i = tx; i < 2048; i += 256) {
            int c = i >> 4, q = i & 15;
            float4 v = W4[(size_t)c * 32 + kt * 16 + q];
            Wt[q * 4 + 0][c] = v.x; Wt[q * 4 + 1][c] = v.y;
            Wt[q * 4 + 2][c] = v.z; Wt[q * 4 + 3][c] = v.w;
        }
        __syncthreads();
        for (int k = 0; k < 64; k += 4) {
            float4 a[8];
            #pragma unroll
            for (int i = 0; i < 8; ++i) a[i] = *(const float4*)&As[rid * 8 + i][k];
            #pragma unroll
            for (int kk = 0; kk < 4; ++kk) {
                float4 w = *(const float4*)&Wt[k + kk][cid * 4];
                #pragma unroll
                for (int i = 0; i < 8; ++i) {
                    float av = (kk == 0) ? a[i].x : (kk == 1) ? a[i].y : (kk == 2) ? a[i].z : a[i].w;
                    acc[i][0] += av * w.x; acc[i][1] += av * w.y;
                    acc[i][2] += av * w.z; acc[i][3] += av * w.w;
                }
            }
        }
        __syncthreads();
    }
    #pragma unroll
    for (int i = 0; i < 8; ++i) {
        int row = row0 + rid * 8 + i;
        if (row < N)
            ((float4*)C)[(size_t)row * 32 + cid] =
                make_float4(acc[i][0], acc[i][1], acc[i][2], acc[i][3]);
    }
    const int hh = cid >> 4;
    const int c0 = (cid & 15) * 4;
    float ad0 = att[hh * 128 + c0 + 0], ad1 = att[hh * 128 + c0 + 1];
    float ad2c = att[hh * 128 + c0 + 2], ad3 = att[hh * 128 + c0 + 3];
    float as0 = att[hh * 128 + 64 + c0 + 0], as1 = att[hh * 128 + 64 + c0 + 1];
    float as2 = att[hh * 128 + 64 + c0 + 2], as3 = att[hh * 128 + 64 + c0 + 3];
    float pd[8], ps[8];
    #pragma unroll
    for (int i = 0; i < 8; ++i) {
        pd[i] = acc[i][0] * ad0 + acc[i][1] * ad1 + acc[i][2] * ad2c + acc[i][3] * ad3;
        ps[i] = acc[i][0] * as0 + acc[i][1] * as1 + acc[i][2] * as2 + acc[i][3] * as3;
    }
    #pragma unroll
    for (int m = 1; m < 16; m <<= 1) {
        #pragma unroll
        for (int i = 0; i < 8; ++i) {
            pd[i] += __shfl_xor(pd[i], m);
            ps[i] += __shfl_xor(ps[i], m);
        }
    }
    const int ll = tx & 63;
    const int grp = ll & 32;
    #pragma unroll
    for (int i = 0; i < 8; ++i) {
        float d0 = __shfl(pd[i], grp + 0);
        float d1 = __shfl(pd[i], grp + 16);
        float s0 = __shfl(ps[i], grp + 0);
        float s1 = __shfl(ps[i], grp + 16);
        if ((ll & 31) == 0) {
            int row = row0 + rid * 8 + i;
            if (row < N) {
                ad2v[row] = make_float2(d0, d1);
                ni4[row] = make_float4(s0, s1, 0.f, 0.f);
            }
        }
    }
}

// ---------------------- dual CSR build (once) ------------------------------
__global__ __launch_bounds__(256) void hist_both(const int* __restrict__ ei, int E,
                                                 unsigned int* __restrict__ dd,
                                                 unsigned int* __restrict__ ds) {
    int e = blockIdx.x * 256 + threadIdx.x;
    if (e < E) {
        atomicAdd(&ds[ei[e]], 1u);
        atomicAdd(&dd[ei[E + e]], 1u);
    }
}

// dual per-block scan; +1 per element folds in the self-loop.
__global__ __launch_bounds__(256) void scan_p1(const unsigned int* __restrict__ deg_d,
                                               const unsigned int* __restrict__ deg_s,
                                               unsigned int* __restrict__ off_dv,
                                               unsigned int* __restrict__ off_sv,
                                               unsigned int* __restrict__ bsum_dv,
                                               unsigned int* __restrict__ bsum_sv,
                                               int N, int NB) {
    __shared__ unsigned int sh[256];
    const bool isS = (int)blockIdx.x >= NB;
    const unsigned int* deg = isS ? deg_s : deg_d;
    unsigned int* off  = isS ? off_sv  : off_dv;
    unsigned int* bsum = isS ? bsum_sv : bsum_dv;
    const int blk = isS ? (blockIdx.x - NB) : blockIdx.x;
    int t = threadIdx.x;
    int base = blk * 1024 + t * 4;
    unsigned int v0 = 0, v1 = 0, v2 = 0, v3 = 0;
    if (base + 3 < N) {
        uint4 q = *(const uint4*)&deg[base];
        v0 = q.x + 1u; v1 = q.y + 1u; v2 = q.z + 1u; v3 = q.w + 1u;
    } else {
        if (base + 0 < N) v0 = deg[base + 0] + 1u;
        if (base + 1 < N) v1 = deg[base + 1] + 1u;
        if (base + 2 < N) v2 = deg[base + 2] + 1u;
        if (base + 3 < N) v3 = deg[base + 3] + 1u;
    }
    sh[t] = v0 + v1 + v2 + v3;
    __syncthreads();
    #pragma unroll
    for (int d = 1; d < 256; d <<= 1) {
        unsigned int u = (t >= d) ? sh[t - d] : 0u;
        __syncthreads();
        sh[t] += u;
        __syncthreads();
    }
    unsigned int ex = (t == 0) ? 0u : sh[t - 1];
    if (base + 3 < N) {
        *(uint4*)&off[base] = make_uint4(ex, ex + v0, ex + v0 + v1, ex + v0 + v1 + v2);
    } else {
        if (base + 0 < N) off[base + 0] = ex;
        if (base + 1 < N) off[base + 1] = ex + v0;
        if (base + 2 < N) off[base + 2] = ex + v0 + v1;
        if (base + 3 < N) off[base + 3] = ex + v0 + v1 + v2;
    }
    if (t == 255) bsum[blk] = sh[255];
}

__global__ __launch_bounds__(1024) void scan_p2(unsigned int* __restrict__ bsum_d,
                                                unsigned int* __restrict__ bsum_s, int NB) {
    __shared__ unsigned int sh[1024];
    unsigned int* bsum = blockIdx.x ? bsum_s : bsum_d;
    int t = threadIdx.x;
    sh[t] = (t < NB) ? bsum[t] : 0u;
    __syncthreads();
    #pragma unroll
    for (int d = 1; d < 1024; d <<= 1) {
        unsigned int u = (t >= d) ? sh[t - d] : 0u;
        __syncthreads();
        sh[t] += u;
        __syncthreads();
    }
    if (t < NB) bsum[t] = (t == 0) ? 0u : sh[t - 1];
}

// add block sums; seed coarse-bucket cursors; off[N]=Et.
__global__ __launch_bounds__(256) void scan_p3(unsigned int* __restrict__ off_dv,
                                               unsigned int* __restrict__ off_sv,
                                               const unsigned int* __restrict__ bsum_dv,
                                               const unsigned int* __restrict__ bsum_sv,
                                               unsigned int* __restrict__ cur_dv,
                                               unsigned int* __restrict__ cur_sv,
                                               int N, unsigned int total, int half) {
    const bool isS = (int)blockIdx.x >= half;
    unsigned int* off = isS ? off_sv : off_dv;
    const unsigned int* bsum = isS ? bsum_sv : bsum_dv;
    unsigned int* cur = isS ? cur_sv : cur_dv;
    const int blk = isS ? (blockIdx.x - half) : blockIdx.x;
    int i = blk * 256 + threadIdx.x;
    if (i < N) {
        unsigned int v = off[i] + bsum[i >> 10];
        off[i] = v;
        if ((i & 63) == 0) cur[i >> 6] = v;
    }
    if (i == N) off[N] = total;
}

// MSD pass 1: bucket edges by key>>6 into block-reserved contiguous runs.
template <bool BYDST>
__global__ __launch_bounds__(512) void coarse_scatter(const int* __restrict__ ei, int E, int Et,
                                                      unsigned int* __restrict__ cur,
                                                      unsigned int* __restrict__ tmp, int CB) {
    __shared__ unsigned int lh[800];
    const int t = threadIdx.x;
    for (int b = t; b < CB; b += 512) lh[b] = 0u;
    __syncthreads();
    const int i0 = blockIdx.x * EPB;
    for (int i = t; i < EPB; i += 512) {
        int e = i0 + i;
        if (e < Et) {
            int k = (e < E) ? ei[BYDST ? (E + e) : e] : (e - E);
            atomicAdd(&lh[k >> 6], 1u);
        }
    }
    __syncthreads();
    for (int b = t; b < CB; b += 512) {
        unsigned int c = lh[b];
        lh[b] = atomicAdd(&cur[b], c);
    }
    __syncthreads();
    for (int i = t; i < EPB; i += 512) {
        int e = i0 + i;
        if (e < Et) {
            int s, d;
            if (e < E) { s = ei[e]; d = ei[E + e]; } else { s = d = e - E; }
            int k = BYDST ? d : s;
            int v = BYDST ? s : d;
            unsigned int pos = atomicAdd(&lh[k >> 6], 1u);
            tmp[pos] = ((unsigned int)(k & 63) << 16) | (unsigned int)v;
        }
    }
}

// MSD pass 2: one block per 64-node bucket; LDS cursors = global off values.
__global__ __launch_bounds__(256) void fine_sort(const unsigned int* __restrict__ tmp,
                                                 const unsigned int* __restrict__ off,
                                                 int* __restrict__ outv, int N) {
    __shared__ unsigned int h[64];
    const int b = blockIdx.x;
    const int node0 = b * 64;
    int nn = N - node0; if (nn > 64) nn = 64;
    const int t = threadIdx.x;
    if (t < nn) h[t] = off[node0 + t];
    __syncthreads();
    unsigned int base = off[node0];
    unsigned int end = off[node0 + nn];
    for (unsigned int i = base + t; i < end; i += 256) {
        unsigned int v = tmp[i];
        unsigned int pos = atomicAdd(&h[v >> 16], 1u);
        outv[pos] = (int)(v & 0xFFFFu);
    }
}

// ---- softmax denominator per src node: gather a_dst over out-edges --------
__global__ __launch_bounds__(256) void src_sum(const int* __restrict__ dsts,
                                               const unsigned int* __restrict__ off_s,
                                               const float2* __restrict__ ad2,
                                               float* __restrict__ ni, int N) {
    int n = blockIdx.x * 256 + threadIdx.x;
    if (n >= N) return;
    float as0 = ni[(size_t)n * 4 + 0];
    float as1 = ni[(size_t)n * 4 + 1];
    unsigned int j0 = off_s[n], j1 = off_s[n + 1];
    float s0 = 0.f, s1 = 0.f;
    unsigned int j = j0;
    for (; j + 4 <= j1; j += 4) {
        int d0 = dsts[j], d1 = dsts[j + 1], d2 = dsts[j + 2], d3 = dsts[j + 3];
        float2 a0 = ad2[d0], a1 = ad2[d1], a2 = ad2[d2], a3 = ad2[d3];
        float t;
        t = as0 + a0.x; t = (t > 0.f) ? t : 0.2f * t; s0 += __expf(t);
        t = as1 + a0.y; t = (t > 0.f) ? t : 0.2f * t; s1 += __expf(t);
        t = as0 + a1.x; t = (t > 0.f) ? t : 0.2f * t; s0 += __expf(t);
        t = as1 + a1.y; t = (t > 0.f) ? t : 0.2f * t; s1 += __expf(t);
        t = as0 + a2.x; t = (t > 0.f) ? t : 0.2f * t; s0 += __expf(t);
        t = as1 + a2.y; t = (t > 0.f) ? t : 0.2f * t; s1 += __expf(t);
        t = as0 + a3.x; t = (t > 0.f) ? t : 0.2f * t; s0 += __expf(t);
        t = as1 + a3.y; t = (t > 0.f) ? t : 0.2f * t; s1 += __expf(t);
    }
    for (; j < j1; ++j) {
        float2 a = ad2[dsts[j]];
        float t;
        t = as0 + a.x; t = (t > 0.f) ? t : 0.2f * t; s0 += __expf(t);
        t = as1 + a.y; t = (t > 0.f) ? t : 0.2f * t; s1 += __expf(t);
    }
    ni[(size_t)n * 4 + 2] = 1.0f / (s0 + 1e-16f);
    ni[(size_t)n * 4 + 3] = 1.0f / (s1 + 1e-16f);
}

// ---- per-edge weights in dst-CSR order: one block per 64-node bucket ------
// w2[j] = { exp(lrelu(ad[d]+as[s]))*rcp[s] } for both heads, computed ONCE.
__global__ __launch_bounds__(256) void edge_w(const int* __restrict__ srcs,
                                              const unsigned int* __restrict__ off_d,
                                              const float4* __restrict__ ni4,
                                              const float2* __restrict__ ad2,
                                              float2* __restrict__ w2, int N) {
    __shared__ unsigned int lb[65];
    __shared__ float2 lad[64];
    const int node0 = blockIdx.x * 64;
    int nn = N - node0; if (nn > 64) nn = 64;
    const int t = threadIdx.x;
    if (t <= nn) lb[t] = off_d[node0 + t];
    if (t < nn) lad[t] = ad2[node0 + t];
    __syncthreads();
    unsigned int base = lb[0], end = lb[nn];
    for (unsigned int i = base + t; i < end; i += 256) {
        int lo = 0, hi = nn;
        while (hi - lo > 1) {
            int mid = (lo + hi) >> 1;
            if (i >= lb[mid]) lo = mid; else hi = mid;
        }
        float2 ad = lad[lo];
        int s = srcs[i];
        float4 nv = ni4[s];
        float a0 = ad.x + nv.x; a0 = (a0 > 0.f) ? a0 : 0.2f * a0;
        float a1 = ad.y + nv.y; a1 = (a1 > 0.f) ? a1 : 0.2f * a1;
        w2[i] = make_float2(__expf(a0) * nv.z, __expf(a1) * nv.w);
    }
}

// ---------------- CSR aggregation: one wave per dst node -------------------
template <int U>
__device__ __forceinline__ void agg_edges(unsigned int j, const int* __restrict__ srcs,
                                          const float2* __restrict__ w2,
                                          const float2* __restrict__ x2,
                                          int l, int hi, float& accx, float& accy) {
    int s[U]; float2 w[U]; float2 v[U];
    #pragma unroll
    for (int u = 0; u < U; ++u) s[u] = srcs[j + u];
    #pragma unroll
    for (int u = 0; u < U; ++u) w[u] = w2[j + u];
    #pragma unroll
    for (int u = 0; u < U; ++u) v[u] = x2[(size_t)s[u] * 64 + l];
    #pragma unroll
    for (int u = 0; u < U; ++u) {
        float ww = hi ? w[u].y : w[u].x;
        accx += v[u].x * ww;
        accy += v[u].y * ww;
    }
}

template <bool LAST>
__global__ __launch_bounds__(256) void agg_csr(const int* __restrict__ srcs,
                                               const unsigned int* __restrict__ off,
                                               const float2* __restrict__ x2,
                                               const float2* __restrict__ w2,
                                               const float* __restrict__ bias,
                                               float* __restrict__ out,
                                               const float* __restrict__ Wout,
                                               const float* __restrict__ bout,
                                               float* __restrict__ out3,
                                               float* __restrict__ ypred, int N) {
    int d = blockIdx.x * 4 + (threadIdx.x >> 6);
    int l = threadIdx.x & 63;
    if (d >= N) return;
    d = __builtin_amdgcn_readfirstlane(d);
    const int hi = l >> 5;
    unsigned int j0 = off[d], j1 = off[d + 1];
    float accx = 0.f, accy = 0.f;
    unsigned int j = j0;
    for (; j + 16 <= j1; j += 16) agg_edges<16>(j, srcs, w2, x2, l, hi, accx, accy);
    if (j + 8 <= j1) { agg_edges<8>(j, srcs, w2, x2, l, hi, accx, accy); j += 8; }
    if (j + 4 <= j1) { agg_edges<4>(j, srcs, w2, x2, l, hi, accx, accy); j += 4; }
    if (j + 2 <= j1) { agg_edges<2>(j, srcs, w2, x2, l, hi, accx, accy); j += 2; }
    if (j < j1)      { agg_edges<1>(j, srcs, w2, x2, l, hi, accx, accy); }

    float2 bb = ((const float2*)bias)[l];
    float o0 = fmaxf(accx + bb.x, 0.f);
    float o1 = fmaxf(accy + bb.y, 0.f);
    ((float2*)out)[(size_t)d * 64 + l] = make_float2(o0, o1);
    if (LAST) {
        const float2* W2 = (const float2*)Wout;
        float2 wa = W2[l], wb = W2[64 + l], wc = W2[128 + l];
        float p0 = o0 * wa.x + o1 * wa.y;
        float p1 = o0 * wb.x + o1 * wb.y;
        float p2 = o0 * wc.x + o1 * wc.y;
        #pragma unroll
        for (int m = 32; m; m >>= 1) {
            p0 += __shfl_xor(p0, m);
            p1 += __shfl_xor(p1, m);
            p2 += __shfl_xor(p2, m);
        }
        if (l == 0) {
            p0 += bout[0]; p1 += bout[1]; p2 += bout[2];
            out3[d * 3 + 0] = p0; out3[d * 3 + 1] = p1; out3[d * 3 + 2] = p2;
            int am = 0; float best = p0;
            if (p1 > best) { best = p1; am = 1; }
            if (p2 > best) { best = p2; am = 2; }
            ypred[d] = (float)am;
        }
    }
}

__global__ __launch_bounds__(256) void gather_out(const float* __restrict__ out3,
                                                  const float* __restrict__ ypred,
                                                  const int* __restrict__ node_index,
                                                  float* __restrict__ node_out,
                                                  float* __restrict__ y_nodepred, int M) {
    int i = blockIdx.x * 256 + threadIdx.x;
    if (i >= M) return;
    int idx = node_index[i];
    node_out[i * 3 + 0] = out3[idx * 3 + 0];
    node_out[i * 3 + 1] = out3[idx * 3 + 1];
    node_out[i * 3 + 2] = out3[idx * 3 + 2];
    y_nodepred[i] = ypred[idx];
}

extern "C" void kernel_launch(void* const* d_in, const int* in_sizes, int n_in,
                              void* d_out, int out_size, void* d_ws, size_t ws_size,
                              hipStream_t stream) {
    const float* x          = (const float*)d_in[0];
    const int*   ei         = (const int*)d_in[1];
    const int*   node_index = (const int*)d_in[3];
    const float* W[3]   = {(const float*)d_in[4], (const float*)d_in[7], (const float*)d_in[10]};
    const float* att[3] = {(const float*)d_in[5], (const float*)d_in[8], (const float*)d_in[11]};
    const float* b[3]   = {(const float*)d_in[6], (const float*)d_in[9], (const float*)d_in[12]};
    const float* Wout = (const float*)d_in[13];
    const float* bout = (const float*)d_in[14];

    const int N  = in_sizes[0] / 128;
    const int E  = in_sizes[1] / 2;
    const int Et = E + N;
    const int M  = in_sizes[3];
    const int NB = (N + 1023) / 1024;        // scan blocks per array
    const int CB = (N + 63) / 64;            // coarse buckets
    const int NBLK = (Et + EPB - 1) / EPB;   // coarse scatter blocks

    // workspace layout (floats), ~66 MB total.
    // tmp aliases xlin (CSR build finishes before first gemm writes xlin).
    // out3 aliases ad/ni (both dead before the LAST agg_csr runs).
    float* ws     = (float*)d_ws;
    float* xlin   = ws;                               // N*128
    unsigned int* tmp = (unsigned int*)ws;            // Et (build-time only)
    float* hb     = xlin + (size_t)N * 128;           // N*128
    float* ad     = hb + (size_t)N * 128;             // N*2  (a_dst)
    float* ni     = ad + (size_t)N * 2;               // N*4  {as0,as1,rcp0,rcp1}
    float* out3   = ad;                               // N*3, aliases ad+ni
    unsigned int* off_d = (unsigned int*)(ni + (size_t)N * 4);  // N+4
    unsigned int* off_s = off_d + (size_t)N + 4;       // N+4
    unsigned int* deg_d = off_s + (size_t)N + 4;       // N
    unsigned int* deg_s = deg_d + (size_t)N;           // N
    unsigned int* cur_d = deg_s + (size_t)N;           // CB (pad 1024)
    unsigned int* cur_s = cur_d + 1024;                // CB (pad 1024)
    unsigned int* bsum_d = cur_s + 1024;               // NB (pad 1024)
    unsigned int* bsum_s = bsum_d + 1024;              // NB (pad 1024)
    int* srcs = (int*)(bsum_s + 1024);                 // Et
    int* dsts = srcs + (size_t)Et;                     // Et
    float2* w2 = (float2*)(dsts + (size_t)Et);         // Et float2

    // output layout (floats): x_embed | node_output | ypred | y_nodepred
    float* o_embed = (float*)d_out;
    float* o_node  = o_embed + (size_t)N * 128;
    float* o_ypred = o_node + (size_t)M * 3;
    float* o_ynode = o_ypred + (size_t)N;

    const int gemm_blocks = (N + 63) / 64;
    const int node_wave_blocks = (N + 3) / 4;
    const int n_blocks = (N + 255) / 256;
    const int p3_half = (N + 256) / 256;

    // ---- dual CSR via 2-level MSD bucket sort (built once) ----
    hipMemsetAsync(deg_d, 0, (size_t)2 * N * sizeof(unsigned int), stream);  // deg_d+deg_s
    hist_both<<<(E + 255) / 256, 256, 0, stream>>>(ei, E, deg_d, deg_s);
    scan_p1<<<2 * NB, 256, 0, stream>>>(deg_d, deg_s, off_d, off_s, bsum_d, bsum_s, N, NB);
    scan_p2<<<2, 1024, 0, stream>>>(bsum_d, bsum_s, NB);
    scan_p3<<<2 * p3_half, 256, 0, stream>>>(off_d, off_s, bsum_d, bsum_s, cur_d, cur_s,
                                             N, (unsigned int)Et, p3_half);
    coarse_scatter<true><<<NBLK, 512, 0, stream>>>(ei, E, Et, cur_d, tmp, CB);
    fine_sort<<<CB, 256, 0, stream>>>(tmp, off_d, srcs, N);
    coarse_scatter<false><<<NBLK, 512, 0, stream>>>(ei, E, Et, cur_s, tmp, CB);
    fine_sort<<<CB, 256, 0, stream>>>(tmp, off_s, dsts, N);

    for (int L = 0; L < 3; ++L) {
        const float* hin = (L == 0) ? x : hb;
        gemm128<<<gemm_blocks, 256, 0, stream>>>(hin, W[L], att[L], xlin,
                                                 (float4*)ni, (float2*)ad, N);
        src_sum<<<n_blocks, 256, 0, stream>>>(dsts, off_s, (const float2*)ad, ni, N);
        edge_w<<<CB, 256, 0, stream>>>(srcs, off_d, (const float4*)ni, (const float2*)ad,
                                       w2, N);
        if (L < 2)
            agg_csr<false><<<node_wave_blocks, 256, 0, stream>>>(
                srcs, off_d, (const float2*)xlin, (const float2*)w2,
                b[L], hb, nullptr, nullptr, nullptr, nullptr, N);
        else
            agg_csr<true><<<node_wave_blocks, 256, 0, stream>>>(
                srcs, off_d, (const float2*)xlin, (const float2*)w2,
                b[L], o_embed, Wout, bout, out3, o_ypred, N);
    }
    gather_out<<<(M + 255) / 256, 256, 0, stream>>>(out3, o_ypred, node_index, o_node, o_ynode, M);
}

// Round 9
// 419.313 us; speedup vs baseline: 4.1220x; 1.1249x over previous
//
#include <hip/hip_runtime.h>
#include <math.h>

// ---------------------------------------------------------------------------
// GAT forward (3 layers) on MI355X. f32. N=50000, D=128, H=2, k=64.
// E=800000 real edges + N self-loops (Et=850000).
// Round 9: N-wide histogram+scan deleted. Offsets are now 2-level like the
// sort: coarse LDS hist (782 buckets) -> 1-block coarse scan -> combined
// coarse scatter (both orders, one ei pass) -> fine_sort computes per-node
// off[] in-bucket (64-wide LDS scan) and places values. No N-wide atomics.
// ---------------------------------------------------------------------------

#define EPB 8192   // edges per coarse block

// C = A(N x 128) @ W^T(128 x 128), f32. Epilogue computes the per-node
// attention dots from acc registers (a_dst -> ad2, a_src -> ni.xy).
__global__ __launch_bounds__(256) void gemm128(const float* __restrict__ A,
                                               const float* __restrict__ Wm,
                                               const float* __restrict__ att,
                                               float* __restrict__ C,
                                               float4* __restrict__ ni4,
                                               float2* __restrict__ ad2v, int N) {
    __shared__ float As[64][68];
    __shared__ float Wt[64][132];
    const int tx = threadIdx.x;
    const int row0 = blockIdx.x * 64;
    const int cid = tx & 31;
    const int rid = tx >> 5;
    float acc[8][4] = {};
    const float4* A4 = (const float4*)A;
    const float4* W4 = (const float4*)Wm;

    for (int kt = 0; kt < 2; ++kt) {
        for (int i = tx; i < 1024; i += 256) {
            int r = i >> 4, q = i & 15;
            int row = row0 + r;
            float4 v = (row < N) ? A4[(size_t)row * 32 + kt * 16 + q]
                                 : make_float4(0.f, 0.f, 0.f, 0.f);
            As[r][q * 4 + 0] = v.x; As[r][q * 4 + 1] = v.y;
            As[r][q * 4 + 2] = v.z; As[r][q * 4 + 3] = v.w;
        }
        for (int i = tx; i < 2048; i += 256) {
            int c = i >> 4, q = i & 15;
            float4 v = W4[(size_t)c * 32 + kt * 16 + q];
            Wt[q * 4 + 0][c] = v.x; Wt[q * 4 + 1][c] = v.y;
            Wt[q * 4 + 2][c] = v.z; Wt[q * 4 + 3][c] = v.w;
        }
        __syncthreads();
        for (int k = 0; k < 64; k += 4) {
            float4 a[8];
            #pragma unroll
            for (int i = 0; i < 8; ++i) a[i] = *(const float4*)&As[rid * 8 + i][k];
            #pragma unroll
            for (int kk = 0; kk < 4; ++kk) {
                float4 w = *(const float4*)&Wt[k + kk][cid * 4];
                #pragma unroll
                for (int i = 0; i < 8; ++i) {
                    float av = (kk == 0) ? a[i].x : (kk == 1) ? a[i].y : (kk == 2) ? a[i].z : a[i].w;
                    acc[i][0] += av * w.x; acc[i][1] += av * w.y;
                    acc[i][2] += av * w.z; acc[i][3] += av * w.w;
                }
            }
        }
        __syncthreads();
    }
    #pragma unroll
    for (int i = 0; i < 8; ++i) {
        int row = row0 + rid * 8 + i;
        if (row < N)
            ((float4*)C)[(size_t)row * 32 + cid] =
                make_float4(acc[i][0], acc[i][1], acc[i][2], acc[i][3]);
    }
    const int hh = cid >> 4;
    const int c0 = (cid & 15) * 4;
    float ad0 = att[hh * 128 + c0 + 0], ad1 = att[hh * 128 + c0 + 1];
    float ad2c = att[hh * 128 + c0 + 2], ad3 = att[hh * 128 + c0 + 3];
    float as0 = att[hh * 128 + 64 + c0 + 0], as1 = att[hh * 128 + 64 + c0 + 1];
    float as2 = att[hh * 128 + 64 + c0 + 2], as3 = att[hh * 128 + 64 + c0 + 3];
    float pd[8], ps[8];
    #pragma unroll
    for (int i = 0; i < 8; ++i) {
        pd[i] = acc[i][0] * ad0 + acc[i][1] * ad1 + acc[i][2] * ad2c + acc[i][3] * ad3;
        ps[i] = acc[i][0] * as0 + acc[i][1] * as1 + acc[i][2] * as2 + acc[i][3] * as3;
    }
    #pragma unroll
    for (int m = 1; m < 16; m <<= 1) {
        #pragma unroll
        for (int i = 0; i < 8; ++i) {
            pd[i] += __shfl_xor(pd[i], m);
            ps[i] += __shfl_xor(ps[i], m);
        }
    }
    const int ll = tx & 63;
    const int grp = ll & 32;
    #pragma unroll
    for (int i = 0; i < 8; ++i) {
        float d0 = __shfl(pd[i], grp + 0);
        float d1 = __shfl(pd[i], grp + 16);
        float s0 = __shfl(ps[i], grp + 0);
        float s1 = __shfl(ps[i], grp + 16);
        if ((ll & 31) == 0) {
            int row = row0 + rid * 8 + i;
            if (row < N) {
                ad2v[row] = make_float2(d0, d1);
                ni4[row] = make_float4(s0, s1, 0.f, 0.f);
            }
        }
    }
}

// ----------------------- 2-level CSR build (once) --------------------------
// Coarse histogram of 782 buckets (node>>6), both orders, LDS-privatized.
__global__ __launch_bounds__(512) void coarse_hist(const int* __restrict__ ei, int E, int Et,
                                                   unsigned int* __restrict__ gh_d,
                                                   unsigned int* __restrict__ gh_s, int CB) {
    __shared__ unsigned int lh_d[800];
    __shared__ unsigned int lh_s[800];
    const int t = threadIdx.x;
    for (int b = t; b < CB; b += 512) { lh_d[b] = 0u; lh_s[b] = 0u; }
    __syncthreads();
    const int i0 = blockIdx.x * EPB;
    for (int i = t; i < EPB; i += 512) {
        int e = i0 + i;
        if (e < Et) {
            int s, d;
            if (e < E) { s = ei[e]; d = ei[E + e]; } else { s = d = e - E; }
            atomicAdd(&lh_d[d >> 6], 1u);
            atomicAdd(&lh_s[s >> 6], 1u);
        }
    }
    __syncthreads();
    for (int b = t; b < CB; b += 512) {
        if (lh_d[b]) atomicAdd(&gh_d[b], lh_d[b]);
        if (lh_s[b]) atomicAdd(&gh_s[b], lh_s[b]);
    }
}

// One block scans both 782-entry bucket-count arrays -> bases + cursors.
__global__ __launch_bounds__(1024) void coarse_scan(const unsigned int* __restrict__ gh_d,
                                                    const unsigned int* __restrict__ gh_s,
                                                    unsigned int* __restrict__ coff_d,
                                                    unsigned int* __restrict__ coff_s,
                                                    unsigned int* __restrict__ cur_d,
                                                    unsigned int* __restrict__ cur_s,
                                                    int CB, unsigned int total) {
    __shared__ unsigned int sh[1024];
    const int t = threadIdx.x;
    for (int a = 0; a < 2; ++a) {
        const unsigned int* gh = a ? gh_s : gh_d;
        unsigned int* coff = a ? coff_s : coff_d;
        unsigned int* cur  = a ? cur_s : cur_d;
        sh[t] = (t < CB) ? gh[t] : 0u;
        __syncthreads();
        #pragma unroll
        for (int d = 1; d < 1024; d <<= 1) {
            unsigned int u = (t >= d) ? sh[t - d] : 0u;
            __syncthreads();
            sh[t] += u;
            __syncthreads();
        }
        if (t < CB) {
            unsigned int ex = (t == 0) ? 0u : sh[t - 1];
            coff[t] = ex;
            cur[t] = ex;
        }
        if (t == 0) coff[CB] = total;
        __syncthreads();
    }
}

// One ei pass scatters packed (node&63)<<16|other into BOTH tmp arrays.
__global__ __launch_bounds__(512) void coarse_scatter_both(const int* __restrict__ ei,
                                                           int E, int Et,
                                                           unsigned int* __restrict__ cur_d,
                                                           unsigned int* __restrict__ cur_s,
                                                           unsigned int* __restrict__ tmp_d,
                                                           unsigned int* __restrict__ tmp_s,
                                                           int CB) {
    __shared__ unsigned int lh_d[800];
    __shared__ unsigned int lh_s[800];
    const int t = threadIdx.x;
    for (int b = t; b < CB; b += 512) { lh_d[b] = 0u; lh_s[b] = 0u; }
    __syncthreads();
    const int i0 = blockIdx.x * EPB;
    for (int i = t; i < EPB; i += 512) {
        int e = i0 + i;
        if (e < Et) {
            int s, d;
            if (e < E) { s = ei[e]; d = ei[E + e]; } else { s = d = e - E; }
            atomicAdd(&lh_d[d >> 6], 1u);
            atomicAdd(&lh_s[s >> 6], 1u);
        }
    }
    __syncthreads();
    for (int b = t; b < CB; b += 512) {
        unsigned int cd = lh_d[b], cs = lh_s[b];
        lh_d[b] = cd ? atomicAdd(&cur_d[b], cd) : 0u;
        lh_s[b] = cs ? atomicAdd(&cur_s[b], cs) : 0u;
    }
    __syncthreads();
    for (int i = t; i < EPB; i += 512) {
        int e = i0 + i;
        if (e < Et) {
            int s, d;
            if (e < E) { s = ei[e]; d = ei[E + e]; } else { s = d = e - E; }
            unsigned int pd = atomicAdd(&lh_d[d >> 6], 1u);
            tmp_d[pd] = ((unsigned int)(d & 63) << 16) | (unsigned int)s;
            unsigned int ps = atomicAdd(&lh_s[s >> 6], 1u);
            tmp_s[ps] = ((unsigned int)(s & 63) << 16) | (unsigned int)d;
        }
    }
}

// Per 64-node bucket: LDS hist -> 64-wide scan -> write off[] -> place values.
// Grid 2*CB: first half = dst order (-> off_d, srcs), second = src order.
__global__ __launch_bounds__(256) void fine_sort(const unsigned int* __restrict__ tmp_d,
                                                 const unsigned int* __restrict__ tmp_s,
                                                 const unsigned int* __restrict__ coff_d,
                                                 const unsigned int* __restrict__ coff_s,
                                                 unsigned int* __restrict__ off_d,
                                                 unsigned int* __restrict__ off_s,
                                                 int* __restrict__ srcs,
                                                 int* __restrict__ dsts,
                                                 int N, int CB, unsigned int total) {
    __shared__ unsigned int cnt[64];
    __shared__ unsigned int h[64];
    const bool isS = (int)blockIdx.x >= CB;
    const int b = isS ? (blockIdx.x - CB) : blockIdx.x;
    const unsigned int* tmp  = isS ? tmp_s : tmp_d;
    const unsigned int* coff = isS ? coff_s : coff_d;
    unsigned int* off = isS ? off_s : off_d;
    int* outv = isS ? dsts : srcs;
    const int node0 = b * 64;
    int nn = N - node0; if (nn > 64) nn = 64;
    const int t = threadIdx.x;
    const unsigned int cb0 = coff[b], cb1 = coff[b + 1];
    if (t < 64) cnt[t] = 0u;
    __syncthreads();
    for (unsigned int i = cb0 + t; i < cb1; i += 256)
        atomicAdd(&cnt[tmp[i] >> 16], 1u);
    __syncthreads();
    if (t < 64) h[t] = cnt[t];
    __syncthreads();
    #pragma unroll
    for (int d = 1; d < 64; d <<= 1) {
        unsigned int u = (t < 64 && t >= d) ? h[t - d] : 0u;
        __syncthreads();
        if (t < 64) h[t] += u;
        __syncthreads();
    }
    if (t < 64) h[t] = cb0 + h[t] - cnt[t];   // exclusive base -> cursor
    __syncthreads();
    if (t < nn) off[node0 + t] = h[t];
    if (b == CB - 1 && t == 0) off[N] = total;
    for (unsigned int i = cb0 + t; i < cb1; i += 256) {
        unsigned int v = tmp[i];
        unsigned int pos = atomicAdd(&h[v >> 16], 1u);
        outv[pos] = (int)(v & 0xFFFFu);
    }
}

// ---- softmax denominator per src node: gather a_dst over out-edges --------
__global__ __launch_bounds__(256) void src_sum(const int* __restrict__ dsts,
                                               const unsigned int* __restrict__ off_s,
                                               const float2* __restrict__ ad2,
                                               float* __restrict__ ni, int N) {
    int n = blockIdx.x * 256 + threadIdx.x;
    if (n >= N) return;
    float as0 = ni[(size_t)n * 4 + 0];
    float as1 = ni[(size_t)n * 4 + 1];
    unsigned int j0 = off_s[n], j1 = off_s[n + 1];
    float s0 = 0.f, s1 = 0.f;
    unsigned int j = j0;
    for (; j + 4 <= j1; j += 4) {
        int d0 = dsts[j], d1 = dsts[j + 1], d2 = dsts[j + 2], d3 = dsts[j + 3];
        float2 a0 = ad2[d0], a1 = ad2[d1], a2 = ad2[d2], a3 = ad2[d3];
        float t;
        t = as0 + a0.x; t = (t > 0.f) ? t : 0.2f * t; s0 += __expf(t);
        t = as1 + a0.y; t = (t > 0.f) ? t : 0.2f * t; s1 += __expf(t);
        t = as0 + a1.x; t = (t > 0.f) ? t : 0.2f * t; s0 += __expf(t);
        t = as1 + a1.y; t = (t > 0.f) ? t : 0.2f * t; s1 += __expf(t);
        t = as0 + a2.x; t = (t > 0.f) ? t : 0.2f * t; s0 += __expf(t);
        t = as1 + a2.y; t = (t > 0.f) ? t : 0.2f * t; s1 += __expf(t);
        t = as0 + a3.x; t = (t > 0.f) ? t : 0.2f * t; s0 += __expf(t);
        t = as1 + a3.y; t = (t > 0.f) ? t : 0.2f * t; s1 += __expf(t);
    }
    for (; j < j1; ++j) {
        float2 a = ad2[dsts[j]];
        float t;
        t = as0 + a.x; t = (t > 0.f) ? t : 0.2f * t; s0 += __expf(t);
        t = as1 + a.y; t = (t > 0.f) ? t : 0.2f * t; s1 += __expf(t);
    }
    ni[(size_t)n * 4 + 2] = 1.0f / (s0 + 1e-16f);
    ni[(size_t)n * 4 + 3] = 1.0f / (s1 + 1e-16f);
}

// ---- per-edge weights in dst-CSR order: one block per 64-node bucket ------
__global__ __launch_bounds__(256) void edge_w(const int* __restrict__ srcs,
                                              const unsigned int* __restrict__ off_d,
                                              const float4* __restrict__ ni4,
                                              const float2* __restrict__ ad2,
                                              float2* __restrict__ w2, int N) {
    __shared__ unsigned int lb[65];
    __shared__ float2 lad[64];
    const int node0 = blockIdx.x * 64;
    int nn = N - node0; if (nn > 64) nn = 64;
    const int t = threadIdx.x;
    if (t <= nn) lb[t] = off_d[node0 + t];
    if (t < nn) lad[t] = ad2[node0 + t];
    __syncthreads();
    unsigned int base = lb[0], end = lb[nn];
    for (unsigned int i = base + t; i < end; i += 256) {
        int lo = 0, hi = nn;
        while (hi - lo > 1) {
            int mid = (lo + hi) >> 1;
            if (i >= lb[mid]) lo = mid; else hi = mid;
        }
        float2 ad = lad[lo];
        int s = srcs[i];
        float4 nv = ni4[s];
        float a0 = ad.x + nv.x; a0 = (a0 > 0.f) ? a0 : 0.2f * a0;
        float a1 = ad.y + nv.y; a1 = (a1 > 0.f) ? a1 : 0.2f * a1;
        w2[i] = make_float2(__expf(a0) * nv.z, __expf(a1) * nv.w);
    }
}

// ---------------- CSR aggregation: one wave per dst node -------------------
template <int U>
__device__ __forceinline__ void agg_edges(unsigned int j, const int* __restrict__ srcs,
                                          const float2* __restrict__ w2,
                                          const float2* __restrict__ x2,
                                          int l, int hi, float& accx, float& accy) {
    int s[U]; float2 w[U]; float2 v[U];
    #pragma unroll
    for (int u = 0; u < U; ++u) s[u] = srcs[j + u];
    #pragma unroll
    for (int u = 0; u < U; ++u) w[u] = w2[j + u];
    #pragma unroll
    for (int u = 0; u < U; ++u) v[u] = x2[(size_t)s[u] * 64 + l];
    #pragma unroll
    for (int u = 0; u < U; ++u) {
        float ww = hi ? w[u].y : w[u].x;
        accx += v[u].x * ww;
        accy += v[u].y * ww;
    }
}

template <bool LAST>
__global__ __launch_bounds__(256) void agg_csr(const int* __restrict__ srcs,
                                               const unsigned int* __restrict__ off,
                                               const float2* __restrict__ x2,
                                               const float2* __restrict__ w2,
                                               const float* __restrict__ bias,
                                               float* __restrict__ out,
                                               const float* __restrict__ Wout,
                                               const float* __restrict__ bout,
                                               float* __restrict__ out3,
                                               float* __restrict__ ypred, int N) {
    int d = blockIdx.x * 4 + (threadIdx.x >> 6);
    int l = threadIdx.x & 63;
    if (d >= N) return;
    d = __builtin_amdgcn_readfirstlane(d);
    const int hi = l >> 5;
    unsigned int j0 = off[d], j1 = off[d + 1];
    float accx = 0.f, accy = 0.f;
    unsigned int j = j0;
    for (; j + 16 <= j1; j += 16) agg_edges<16>(j, srcs, w2, x2, l, hi, accx, accy);
    if (j + 8 <= j1) { agg_edges<8>(j, srcs, w2, x2, l, hi, accx, accy); j += 8; }
    if (j + 4 <= j1) { agg_edges<4>(j, srcs, w2, x2, l, hi, accx, accy); j += 4; }
    if (j + 2 <= j1) { agg_edges<2>(j, srcs, w2, x2, l, hi, accx, accy); j += 2; }
    if (j < j1)      { agg_edges<1>(j, srcs, w2, x2, l, hi, accx, accy); }

    float2 bb = ((const float2*)bias)[l];
    float o0 = fmaxf(accx + bb.x, 0.f);
    float o1 = fmaxf(accy + bb.y, 0.f);
    ((float2*)out)[(size_t)d * 64 + l] = make_float2(o0, o1);
    if (LAST) {
        const float2* W2 = (const float2*)Wout;
        float2 wa = W2[l], wb = W2[64 + l], wc = W2[128 + l];
        float p0 = o0 * wa.x + o1 * wa.y;
        float p1 = o0 * wb.x + o1 * wb.y;
        float p2 = o0 * wc.x + o1 * wc.y;
        #pragma unroll
        for (int m = 32; m; m >>= 1) {
            p0 += __shfl_xor(p0, m);
            p1 += __shfl_xor(p1, m);
            p2 += __shfl_xor(p2, m);
        }
        if (l == 0) {
            p0 += bout[0]; p1 += bout[1]; p2 += bout[2];
            out3[d * 3 + 0] = p0; out3[d * 3 + 1] = p1; out3[d * 3 + 2] = p2;
            int am = 0; float best = p0;
            if (p1 > best) { best = p1; am = 1; }
            if (p2 > best) { best = p2; am = 2; }
            ypred[d] = (float)am;
        }
    }
}

__global__ __launch_bounds__(256) void gather_out(const float* __restrict__ out3,
                                                  const float* __restrict__ ypred,
                                                  const int* __restrict__ node_index,
                                                  float* __restrict__ node_out,
                                                  float* __restrict__ y_nodepred, int M) {
    int i = blockIdx.x * 256 + threadIdx.x;
    if (i >= M) return;
    int idx = node_index[i];
    node_out[i * 3 + 0] = out3[idx * 3 + 0];
    node_out[i * 3 + 1] = out3[idx * 3 + 1];
    node_out[i * 3 + 2] = out3[idx * 3 + 2];
    y_nodepred[i] = ypred[idx];
}

extern "C" void kernel_launch(void* const* d_in, const int* in_sizes, int n_in,
                              void* d_out, int out_size, void* d_ws, size_t ws_size,
                              hipStream_t stream) {
    const float* x          = (const float*)d_in[0];
    const int*   ei         = (const int*)d_in[1];
    const int*   node_index = (const int*)d_in[3];
    const float* W[3]   = {(const float*)d_in[4], (const float*)d_in[7], (const float*)d_in[10]};
    const float* att[3] = {(const float*)d_in[5], (const float*)d_in[8], (const float*)d_in[11]};
    const float* b[3]   = {(const float*)d_in[6], (const float*)d_in[9], (const float*)d_in[12]};
    const float* Wout = (const float*)d_in[13];
    const float* bout = (const float*)d_in[14];

    const int N  = in_sizes[0] / 128;
    const int E  = in_sizes[1] / 2;
    const int Et = E + N;
    const int M  = in_sizes[3];
    const int CB = (N + 63) / 64;            // coarse buckets (782)
    const int NBLK = (Et + EPB - 1) / EPB;   // coarse blocks (104)

    // workspace layout (floats), ~66 MB.
    // tmp_d/tmp_s alias xlin (build finishes before first gemm).
    // out3 aliases ad/ni (dead before the LAST agg_csr).
    float* ws     = (float*)d_ws;
    float* xlin   = ws;                               // N*128
    unsigned int* tmp_d = (unsigned int*)ws;          // Et (build only)
    unsigned int* tmp_s = tmp_d + (size_t)Et;         // Et (build only)
    float* hb     = xlin + (size_t)N * 128;           // N*128
    float* ad     = hb + (size_t)N * 128;             // N*2  (a_dst)
    float* ni     = ad + (size_t)N * 2;               // N*4  {as0,as1,rcp0,rcp1}
    float* out3   = ad;                               // N*3, aliases ad+ni
    unsigned int* off_d = (unsigned int*)(ni + (size_t)N * 4);  // N+4
    unsigned int* off_s = off_d + (size_t)N + 4;       // N+4
    unsigned int* gh_d  = off_s + (size_t)N + 4;       // 1024
    unsigned int* gh_s  = gh_d + 1024;                 // 1024
    unsigned int* coff_d = gh_s + 1024;                // 1024
    unsigned int* coff_s = coff_d + 1024;              // 1024
    unsigned int* cur_d  = coff_s + 1024;              // 1024
    unsigned int* cur_s  = cur_d + 1024;               // 1024
    int* srcs = (int*)(cur_s + 1024);                  // Et
    int* dsts = srcs + (size_t)Et;                     // Et
    float2* w2 = (float2*)(dsts + (size_t)Et);         // Et float2

    // output layout (floats): x_embed | node_output | ypred | y_nodepred
    float* o_embed = (float*)d_out;
    float* o_node  = o_embed + (size_t)N * 128;
    float* o_ypred = o_node + (size_t)M * 3;
    float* o_ynode = o_ypred + (size_t)N;

    const int gemm_blocks = (N + 63) / 64;
    const int node_wave_blocks = (N + 3) / 4;
    const int n_blocks = (N + 255) / 256;

    // ---- 2-level CSR build (once) ----
    hipMemsetAsync(gh_d, 0, 2048 * sizeof(unsigned int), stream);  // gh_d + gh_s
    coarse_hist<<<NBLK, 512, 0, stream>>>(ei, E, Et, gh_d, gh_s, CB);
    coarse_scan<<<1, 1024, 0, stream>>>(gh_d, gh_s, coff_d, coff_s, cur_d, cur_s,
                                        CB, (unsigned int)Et);
    coarse_scatter_both<<<NBLK, 512, 0, stream>>>(ei, E, Et, cur_d, cur_s, tmp_d, tmp_s, CB);
    fine_sort<<<2 * CB, 256, 0, stream>>>(tmp_d, tmp_s, coff_d, coff_s, off_d, off_s,
                                          srcs, dsts, N, CB, (unsigned int)Et);

    for (int L = 0; L < 3; ++L) {
        const float* hin = (L == 0) ? x : hb;
        gemm128<<<gemm_blocks, 256, 0, stream>>>(hin, W[L], att[L], xlin,
                                                 (float4*)ni, (float2*)ad, N);
        src_sum<<<n_blocks, 256, 0, stream>>>(dsts, off_s, (const float2*)ad, ni, N);
        edge_w<<<CB, 256, 0, stream>>>(srcs, off_d, (const float4*)ni, (const float2*)ad,
                                       w2, N);
        if (L < 2)
            agg_csr<false><<<node_wave_blocks, 256, 0, stream>>>(
                srcs, off_d, (const float2*)xlin, (const float2*)w2,
                b[L], hb, nullptr, nullptr, nullptr, nullptr, N);
        else
            agg_csr<true><<<node_wave_blocks, 256, 0, stream>>>(
                srcs, off_d, (const float2*)xlin, (const float2*)w2,
                b[L], o_embed, Wout, bout, out3, o_ypred, N);
    }
    gather_out<<<(M + 255) / 256, 256, 0, stream>>>(out3, o_ypred, node_index, o_node, o_ynode, M);
}